// Round 1
// baseline (401.273 us; speedup 1.0000x reference)
//
#include <hip/hip_runtime.h>

// ---------------------------------------------------------------------------
// CrossScaleSelectiveScan: resize+concat+proj_in -> dual GRU scans -> gate+proj_out
// B=8, C=128, H=W=64.  All GEMMs via v_mfma_f32_16x16x32_bf16.
// ---------------------------------------------------------------------------

typedef __bf16 bf16;
typedef _Float16 f16;
typedef __attribute__((ext_vector_type(8))) __bf16 bf16x8;
typedef __attribute__((ext_vector_type(4))) __bf16 bf16x4;
typedef __attribute__((ext_vector_type(4))) _Float16 f16x4;
typedef __attribute__((ext_vector_type(4))) float f32x4;

__device__ __forceinline__ f32x4 mfma16(bf16x8 a, bf16x8 b, f32x4 c) {
  return __builtin_amdgcn_mfma_f32_16x16x32_bf16(a, b, c, 0, 0, 0);
}
__device__ __forceinline__ float sigm(float x) { return 1.0f / (1.0f + __expf(-x)); }
__device__ __forceinline__ float tanh_fast(float x) {
  float e = __expf(2.0f * x);
  return 1.0f - 2.0f / (e + 1.0f);
}

// ---------------------------------------------------------------------------
// K0: convert all weight matrices to bf16 into ws.
// layout (elements): proj_in_w 49152 | wih_h 49152 | whh_h 49152 | wih_w 49152
//                    | whh_w 49152 | gate_w 16384 | proj_out_w 16384
// ---------------------------------------------------------------------------
__global__ __launch_bounds__(256) void k_prep(
    const float* __restrict__ wpi, const float* __restrict__ wihh,
    const float* __restrict__ whhh, const float* __restrict__ wihw,
    const float* __restrict__ whhw, const float* __restrict__ wg,
    const float* __restrict__ wpo, bf16* __restrict__ dst) {
  int i = blockIdx.x * 256 + threadIdx.x;
  if (i < 49152) dst[i] = (bf16)wpi[i];
  else if (i < 98304) dst[i] = (bf16)wihh[i - 49152];
  else if (i < 147456) dst[i] = (bf16)whhh[i - 98304];
  else if (i < 196608) dst[i] = (bf16)wihw[i - 147456];
  else if (i < 245760) dst[i] = (bf16)whhw[i - 196608];
  else if (i < 262144) dst[i] = (bf16)wg[i - 245760];
  else if (i < 278528) dst[i] = (bf16)wpo[i - 262144];
}

// ---------------------------------------------------------------------------
// K1: per (b,h) row: build resized+concat input tile [64 w][384 c] in LDS,
// then proj_in GEMM (M=128, K=384, N=64) + BN + ReLU.
// Writes x_f32 [b][c][h][w] and x_bf16 [p][c] (p = b*4096+h*64+w).
// ---------------------------------------------------------------------------
__global__ __launch_bounds__(256, 2) void k_projin(
    const float* __restrict__ lp, const float* __restrict__ mp,
    const float* __restrict__ sp, const float* __restrict__ pscale,
    const float* __restrict__ pshift, const bf16* __restrict__ Wpi,
    float* __restrict__ xf, bf16* __restrict__ xb) {
  __shared__ __align__(16) bf16 xin[64][392];  // pad 392: bank-spread, 16B rows
  const int tid = threadIdx.x;
  const int bb = blockIdx.x >> 6;
  const int h = blockIdx.x & 63;

  {  // ---- phase A: resize + concat into LDS ----
    const int wq = tid & 63, cq = tid >> 6;
    // l downsample (128->64), jax triangle antialias: taps 1/8,3/8,3/8,1/8, renorm at edges
    float wy[4]; int iy[4];
    {
      float ssum = 0.f;
#pragma unroll
      for (int dy = 0; dy < 4; ++dy) {
        int y = 2 * h - 1 + dy;
        bool ok = (y >= 0) && (y < 128);
        iy[dy] = ok ? y : 0;
        float w0 = (dy == 0 || dy == 3) ? 0.125f : 0.375f;
        wy[dy] = ok ? w0 : 0.f;
        ssum += wy[dy];
      }
      float inv = 1.f / ssum;
#pragma unroll
      for (int dy = 0; dy < 4; ++dy) wy[dy] *= inv;
    }
    float wx[4]; int ix[4];
    {
      float ssum = 0.f;
#pragma unroll
      for (int dx = 0; dx < 4; ++dx) {
        int xq = 2 * wq - 1 + dx;
        bool ok = (xq >= 0) && (xq < 128);
        ix[dx] = ok ? xq : 0;
        float w0 = (dx == 0 || dx == 3) ? 0.125f : 0.375f;
        wx[dx] = ok ? w0 : 0.f;
        ssum += wx[dx];
      }
      float inv = 1.f / ssum;
#pragma unroll
      for (int dx = 0; dx < 4; ++dx) wx[dx] *= inv;
    }
    // s upsample (32->64): src = 0.5*i - 0.25
    int syA, syB; float wsyA, wsyB;
    {
      int j0 = (h - 1) >> 1;
      float f = (h & 1) ? 0.25f : 0.75f;
      float a = 1.f - f, b2 = f;
      if (j0 < 0) a = 0.f;
      if (j0 + 1 > 31) b2 = 0.f;
      float inv = 1.f / (a + b2);
      wsyA = a * inv; wsyB = b2 * inv;
      syA = j0 < 0 ? 0 : j0;
      syB = (j0 + 1 > 31) ? 31 : (j0 + 1);
    }
    int sxA, sxB; float wsxA, wsxB;
    {
      int j0 = (wq - 1) >> 1;
      float f = (wq & 1) ? 0.25f : 0.75f;
      float a = 1.f - f, b2 = f;
      if (j0 < 0) a = 0.f;
      if (j0 + 1 > 31) b2 = 0.f;
      float inv = 1.f / (a + b2);
      wsxA = a * inv; wsxB = b2 * inv;
      sxA = j0 < 0 ? 0 : j0;
      sxB = (j0 + 1 > 31) ? 31 : (j0 + 1);
    }
    for (int ci = 0; ci < 32; ++ci) {
      int c = cq * 32 + ci;
      const float* lc = lp + ((size_t)(bb * 128 + c) << 14);
      float acc = 0.f;
#pragma unroll
      for (int dy = 0; dy < 4; ++dy) {
        const float* row = lc + (iy[dy] << 7);
        float rs = wx[0] * row[ix[0]] + wx[1] * row[ix[1]] +
                   wx[2] * row[ix[2]] + wx[3] * row[ix[3]];
        acc = fmaf(wy[dy], rs, acc);
      }
      xin[wq][c] = (bf16)acc;
      xin[wq][128 + c] = (bf16)mp[((bb * 128 + c) * 64 + h) * 64 + wq];
      const float* sc = sp + ((size_t)(bb * 128 + c) << 10);
      float sv = wsyA * (wsxA * sc[(syA << 5) + sxA] + wsxB * sc[(syA << 5) + sxB]) +
                 wsyB * (wsxA * sc[(syB << 5) + sxA] + wsxB * sc[(syB << 5) + sxB]);
      xin[wq][256 + c] = (bf16)sv;
    }
  }
  __syncthreads();

  // ---- phase B: MFMA proj_in ----
  const int lane = tid & 63, wv = tid >> 6;
  const int l16 = lane & 15, k8 = (lane >> 4) * 8, j4 = (lane >> 4) * 4;
  const f32x4 zf = {0.f, 0.f, 0.f, 0.f};
  f32x4 acc[2][4];
#pragma unroll
  for (int i = 0; i < 2; ++i)
#pragma unroll
    for (int pt = 0; pt < 4; ++pt) acc[i][pt] = zf;

  for (int kk = 0; kk < 12; ++kk) {
    bf16x8 bfr[4];
#pragma unroll
    for (int pt = 0; pt < 4; ++pt)
      bfr[pt] = *(const bf16x8*)&xin[pt * 16 + l16][kk * 32 + k8];
#pragma unroll
    for (int i = 0; i < 2; ++i) {
      bf16x8 afr = *(const bf16x8*)(Wpi + (size_t)((wv * 2 + i) * 16 + l16) * 384 + kk * 32 + k8);
#pragma unroll
      for (int pt = 0; pt < 4; ++pt) acc[i][pt] = mfma16(afr, bfr[pt], acc[i][pt]);
    }
  }
#pragma unroll
  for (int i = 0; i < 2; ++i) {
    int c0 = (wv * 2 + i) * 16 + j4;
    f32x4 scv = *(const f32x4*)&pscale[c0];
    f32x4 shv = *(const f32x4*)&pshift[c0];
#pragma unroll
    for (int pt = 0; pt < 4; ++pt) {
      int pw = pt * 16 + l16;
      bf16x4 pk;
#pragma unroll
      for (int j = 0; j < 4; ++j) {
        float v = fmaxf(acc[i][pt][j] * scv[j] + shv[j], 0.f);
        xf[(size_t)((bb * 128 + c0 + j) * 64 + h) * 64 + pw] = v;
        pk[j] = (bf16)v;
      }
      *(bf16x4*)&xb[(size_t)(bb * 4096 + h * 64 + pw) * 128 + c0] = pk;
    }
  }
}

// ---------------------------------------------------------------------------
// K2: gx = x * wih^T + bih for both directions (M=384, K=128, 32 pixels/block)
// written fp16 in scan order [t][n][384].
// ---------------------------------------------------------------------------
__global__ __launch_bounds__(256, 2) void k_gx(
    const bf16* __restrict__ xb, const bf16* __restrict__ wih_h_b,
    const bf16* __restrict__ wih_w_b, const float* __restrict__ bih_h,
    const float* __restrict__ bih_w, f16* __restrict__ gxh, f16* __restrict__ gxw) {
  const int dir = blockIdx.y;
  const bf16* wih = dir ? wih_w_b : wih_h_b;
  const float* bih = dir ? bih_w : bih_h;
  f16* gx = dir ? gxw : gxh;
  const int p0 = blockIdx.x * 32;
  const int tid = threadIdx.x, lane = tid & 63, wv = tid >> 6;
  const int l16 = lane & 15, k8 = (lane >> 4) * 8, j4 = (lane >> 4) * 4;
  const f32x4 zf = {0.f, 0.f, 0.f, 0.f};
  f32x4 acc[6][2];
#pragma unroll
  for (int i = 0; i < 6; ++i) { acc[i][0] = zf; acc[i][1] = zf; }

#pragma unroll
  for (int kk = 0; kk < 4; ++kk) {
    bf16x8 bfr[2];
#pragma unroll
    for (int pt = 0; pt < 2; ++pt)
      bfr[pt] = *(const bf16x8*)&xb[(size_t)(p0 + pt * 16 + l16) * 128 + kk * 32 + k8];
#pragma unroll
    for (int i = 0; i < 6; ++i) {
      bf16x8 afr = *(const bf16x8*)(wih + (size_t)((wv * 6 + i) * 16 + l16) * 128 + kk * 32 + k8);
#pragma unroll
      for (int pt = 0; pt < 2; ++pt) acc[i][pt] = mfma16(afr, bfr[pt], acc[i][pt]);
    }
  }
#pragma unroll
  for (int i = 0; i < 6; ++i) {
    int g0 = (wv * 6 + i) * 16 + j4;
    f32x4 bi = *(const f32x4*)&bih[g0];
#pragma unroll
    for (int pt = 0; pt < 2; ++pt) {
      int p = p0 + pt * 16 + l16;
      int pb = p >> 12, ph = (p >> 6) & 63, pw = p & 63;
      int t = dir ? pw : ph;
      int n = pb * 64 + (dir ? ph : pw);
      f16x4 pk;
#pragma unroll
      for (int j = 0; j < 4; ++j) pk[j] = (f16)(acc[i][pt][j] + bi[j]);
      *(f16x4*)&gx[((size_t)t * 512 + n) * 384 + g0] = pk;
    }
  }
}

// ---------------------------------------------------------------------------
// K3: GRU scans. 64 blocks: dir = bid>>5, 16 batch-rows each, 64 serial steps.
// whh fragments hoisted to registers; h kept f32 in LDS (bf16 copy for MFMA).
// ---------------------------------------------------------------------------
__global__ __launch_bounds__(256, 1) void k_scan(
    const bf16* __restrict__ whh_h_b, const bf16* __restrict__ whh_w_b,
    const float* __restrict__ bhh_h, const float* __restrict__ bhh_w,
    const f16* __restrict__ gxh, const f16* __restrict__ gxw,
    f16* __restrict__ ohb, f16* __restrict__ owb) {
  const int dir = blockIdx.x >> 5;
  const int nbase = (blockIdx.x & 31) * 16;
  const bf16* whh = dir ? whh_w_b : whh_h_b;
  const float* bhh = dir ? bhh_w : bhh_h;
  const f16* gx = dir ? gxw : gxh;
  f16* outb = dir ? owb : ohb;

  __shared__ __align__(16) bf16 hbf[16][136];
  __shared__ __align__(16) float hf[16][132];
  __shared__ __align__(16) float gh[16][388];

  const int tid = threadIdx.x, lane = tid & 63, wv = tid >> 6;
  const int l16 = lane & 15, k8 = (lane >> 4) * 8, j4 = (lane >> 4) * 4;

  bf16x8 afr[6][4];
#pragma unroll
  for (int i = 0; i < 6; ++i)
#pragma unroll
    for (int kk = 0; kk < 4; ++kk)
      afr[i][kk] = *(const bf16x8*)(whh + (size_t)((wv * 6 + i) * 16 + l16) * 128 + kk * 32 + k8);

  for (int i = tid; i < 16 * 136; i += 256) ((bf16*)hbf)[i] = (bf16)0.f;
  for (int i = tid; i < 16 * 132; i += 256) ((float*)hf)[i] = 0.f;

  const int c = tid & 127, r0 = tid >> 7;
  const float bhr = bhh[c], bhz = bhh[128 + c], bhn = bhh[256 + c];
  int pb_[8];
  const int pstep = dir ? 1 : 64;
#pragma unroll
  for (int it = 0; it < 8; ++it) {
    int n = nbase + r0 + 2 * it;
    int nb2 = n >> 6, q = n & 63;
    pb_[it] = nb2 * 4096 + (dir ? q * 64 : q);
  }
  __syncthreads();

  const f32x4 zf = {0.f, 0.f, 0.f, 0.f};
  for (int t = 0; t < 64; ++t) {
    // prefetch gx for this step (hides HBM latency under MFMA phase)
    const f16* gxb = gx + ((size_t)t * 512 + nbase) * 384;
    f16 gr[8], gz[8], gn[8];
#pragma unroll
    for (int it = 0; it < 8; ++it) {
      int ro = (r0 + 2 * it) * 384;
      gr[it] = gxb[ro + c];
      gz[it] = gxb[ro + 128 + c];
      gn[it] = gxb[ro + 256 + c];
    }
    // gh = h @ whh^T
    f32x4 acc[6];
#pragma unroll
    for (int i = 0; i < 6; ++i) acc[i] = zf;
    bf16x8 bfr[4];
#pragma unroll
    for (int kk = 0; kk < 4; ++kk)
      bfr[kk] = *(const bf16x8*)&hbf[l16][kk * 32 + k8];
#pragma unroll
    for (int i = 0; i < 6; ++i)
#pragma unroll
      for (int kk = 0; kk < 4; ++kk) acc[i] = mfma16(afr[i][kk], bfr[kk], acc[i]);
#pragma unroll
    for (int i = 0; i < 6; ++i) {
      int g0 = (wv * 6 + i) * 16 + j4;
      *(f32x4*)&gh[l16][g0] = acc[i];
    }
    __syncthreads();
    // gates + state update (wave-parallel over (c,row))
#pragma unroll
    for (int it = 0; it < 8; ++it) {
      int row = r0 + 2 * it;
      float rg = sigm((float)gr[it] + gh[row][c] + bhr);
      float zg = sigm((float)gz[it] + gh[row][c + 128] + bhz);
      float ng = tanh_fast((float)gn[it] + rg * (gh[row][c + 256] + bhn));
      float hold = hf[row][c];
      float hnew = (1.f - zg) * ng + zg * hold;
      hf[row][c] = hnew;
      hbf[row][c] = (bf16)hnew;
      outb[(size_t)(pb_[it] + t * pstep) * 128 + c] = (f16)hnew;
    }
    __syncthreads();
  }
}

// ---------------------------------------------------------------------------
// K4: scanned = oh+ow; gate = sigmoid(scanned@gate_w^T + b); gated = scanned*gate;
// out = relu(gated@proj_out^T * scale + shift) + x.  One (b,h) row per block.
// ---------------------------------------------------------------------------
__global__ __launch_bounds__(256, 2) void k_final(
    const f16* __restrict__ ohb, const f16* __restrict__ owb,
    const bf16* __restrict__ Wg, const float* __restrict__ gate_b,
    const bf16* __restrict__ Wpo, const float* __restrict__ poscale,
    const float* __restrict__ poshift, const float* __restrict__ xf,
    float* __restrict__ out) {
  __shared__ __align__(16) float sf[64][132];
  __shared__ __align__(16) bf16 sb[64][136];
  __shared__ __align__(16) bf16 gbuf[64][136];
  const int tid = threadIdx.x;
  const int bb = blockIdx.x >> 6, h = blockIdx.x & 63;
  const int pbase = bb * 4096 + h * 64;
  for (int i = tid; i < 8192; i += 256) {
    int w = i >> 7, cc = i & 127;
    size_t idx = (size_t)(pbase + w) * 128 + cc;
    float v = (float)ohb[idx] + (float)owb[idx];
    sf[w][cc] = v;
    sb[w][cc] = (bf16)v;
  }
  __syncthreads();
  const int lane = tid & 63, wv = tid >> 6;
  const int l16 = lane & 15, k8 = (lane >> 4) * 8, j4 = (lane >> 4) * 4;
  const f32x4 zf = {0.f, 0.f, 0.f, 0.f};
  f32x4 acc[2][4];
#pragma unroll
  for (int i = 0; i < 2; ++i)
#pragma unroll
    for (int pt = 0; pt < 4; ++pt) acc[i][pt] = zf;
#pragma unroll
  for (int kk = 0; kk < 4; ++kk) {
    bf16x8 bfr[4];
#pragma unroll
    for (int pt = 0; pt < 4; ++pt)
      bfr[pt] = *(const bf16x8*)&sb[pt * 16 + l16][kk * 32 + k8];
#pragma unroll
    for (int i = 0; i < 2; ++i) {
      bf16x8 afr = *(const bf16x8*)(Wg + (size_t)((wv * 2 + i) * 16 + l16) * 128 + kk * 32 + k8);
#pragma unroll
      for (int pt = 0; pt < 4; ++pt) acc[i][pt] = mfma16(afr, bfr[pt], acc[i][pt]);
    }
  }
#pragma unroll
  for (int i = 0; i < 2; ++i) {
    int o0 = (wv * 2 + i) * 16 + j4;
    f32x4 gb4 = *(const f32x4*)&gate_b[o0];
#pragma unroll
    for (int pt = 0; pt < 4; ++pt) {
      int pc = pt * 16 + l16;
      f32x4 sv = *(const f32x4*)&sf[pc][o0];
      bf16x4 pk;
#pragma unroll
      for (int j = 0; j < 4; ++j) {
        float g = sigm(acc[i][pt][j] + gb4[j]);
        pk[j] = (bf16)(sv[j] * g);
      }
      *(bf16x4*)&gbuf[pc][o0] = pk;
    }
  }
  __syncthreads();
  f32x4 acc2[2][4];
#pragma unroll
  for (int i = 0; i < 2; ++i)
#pragma unroll
    for (int pt = 0; pt < 4; ++pt) acc2[i][pt] = zf;
#pragma unroll
  for (int kk = 0; kk < 4; ++kk) {
    bf16x8 bfr[4];
#pragma unroll
    for (int pt = 0; pt < 4; ++pt)
      bfr[pt] = *(const bf16x8*)&gbuf[pt * 16 + l16][kk * 32 + k8];
#pragma unroll
    for (int i = 0; i < 2; ++i) {
      bf16x8 afr = *(const bf16x8*)(Wpo + (size_t)((wv * 2 + i) * 16 + l16) * 128 + kk * 32 + k8);
#pragma unroll
      for (int pt = 0; pt < 4; ++pt) acc2[i][pt] = mfma16(afr, bfr[pt], acc2[i][pt]);
    }
  }
#pragma unroll
  for (int i = 0; i < 2; ++i) {
    int o0 = (wv * 2 + i) * 16 + j4;
    f32x4 scv = *(const f32x4*)&poscale[o0];
    f32x4 shv = *(const f32x4*)&poshift[o0];
#pragma unroll
    for (int pt = 0; pt < 4; ++pt) {
      int pc = pt * 16 + l16;
#pragma unroll
      for (int j = 0; j < 4; ++j) {
        int oc = o0 + j;
        size_t oi = (size_t)((bb * 128 + oc) * 64 + h) * 64 + pc;
        float v = fmaxf(acc2[i][pt][j] * scv[j] + shv[j], 0.f) + xf[oi];
        out[oi] = v;
      }
    }
  }
}

// ---------------------------------------------------------------------------
// ws layout (bytes):
//   [0, 557056)            weights bf16
//   [557056, 17334272)     x f32      [b][c][h][w]
//   [17334272, 25722880)   x bf16     [p][c]
//   [25722880, 50888704)   gx_h f16   [t][n][384]
//   [50888704, 76054528)   gx_w f16
//   [76054528, 84443136)   oh f16     [p][c]
//   [84443136, 92831744)   ow f16
// ---------------------------------------------------------------------------
extern "C" void kernel_launch(void* const* d_in, const int* in_sizes, int n_in,
                              void* d_out, int out_size, void* d_ws, size_t ws_size,
                              hipStream_t stream) {
  const float* lp = (const float*)d_in[0];
  const float* mp = (const float*)d_in[1];
  const float* sp = (const float*)d_in[2];
  const float* proj_in_w = (const float*)d_in[3];
  const float* proj_in_scale = (const float*)d_in[4];
  const float* proj_in_shift = (const float*)d_in[5];
  const float* wih_h = (const float*)d_in[6];
  const float* whh_h = (const float*)d_in[7];
  const float* bih_h = (const float*)d_in[8];
  const float* bhh_h = (const float*)d_in[9];
  const float* wih_w = (const float*)d_in[10];
  const float* whh_w = (const float*)d_in[11];
  const float* bih_w = (const float*)d_in[12];
  const float* bhh_w = (const float*)d_in[13];
  const float* gate_w = (const float*)d_in[14];
  const float* gate_b = (const float*)d_in[15];
  const float* proj_out_w = (const float*)d_in[16];
  const float* proj_out_scale = (const float*)d_in[17];
  const float* proj_out_shift = (const float*)d_in[18];
  float* out = (float*)d_out;

  char* ws = (char*)d_ws;
  bf16* wb = (bf16*)ws;
  bf16* Wpi_b = wb + 0;
  bf16* Wih_h_b = wb + 49152;
  bf16* Whh_h_b = wb + 98304;
  bf16* Wih_w_b = wb + 147456;
  bf16* Whh_w_b = wb + 196608;
  bf16* Wg_b = wb + 245760;
  bf16* Wpo_b = wb + 262144;
  float* xf = (float*)(ws + 557056);
  bf16* xb = (bf16*)(ws + 17334272);
  f16* gxh = (f16*)(ws + 25722880);
  f16* gxw = (f16*)(ws + 50888704);
  f16* ohb = (f16*)(ws + 76054528);
  f16* owb = (f16*)(ws + 84443136);

  k_prep<<<dim3(1088), dim3(256), 0, stream>>>(proj_in_w, wih_h, whh_h, wih_w,
                                               whh_w, gate_w, proj_out_w, wb);
  k_projin<<<dim3(512), dim3(256), 0, stream>>>(lp, mp, sp, proj_in_scale,
                                                proj_in_shift, Wpi_b, xf, xb);
  k_gx<<<dim3(1024, 2), dim3(256), 0, stream>>>(xb, Wih_h_b, Wih_w_b, bih_h,
                                                bih_w, gxh, gxw);
  k_scan<<<dim3(64), dim3(256), 0, stream>>>(Whh_h_b, Whh_w_b, bhh_h, bhh_w,
                                             gxh, gxw, ohb, owb);
  k_final<<<dim3(512), dim3(256), 0, stream>>>(ohb, owb, Wg_b, gate_b, Wpo_b,
                                               proj_out_scale, proj_out_shift,
                                               xf, out);
}

// Round 2
// 309.224 us; speedup vs baseline: 1.2977x; 1.2977x over previous
//
#include <hip/hip_runtime.h>

// ---------------------------------------------------------------------------
// CrossScaleSelectiveScan: resize+concat+proj_in -> dual GRU scans -> gate+proj_out
// B=8, C=128, H=W=64.  All GEMMs via v_mfma_f32_16x16x32_bf16.
// R1: k_scan restructured: reg-resident gates (wave w owns gate rows
//     {w*16, 128+w*16, 256+w*16}), h in registers, double-buffered h-LDS,
//     ONE barrier/step, gx prefetched in fragment layout. k_gx emits that
//     layout with biases folded. xbT added so both dirs are symmetric.
// ---------------------------------------------------------------------------

typedef __bf16 bf16;
typedef _Float16 f16;
typedef __attribute__((ext_vector_type(8))) __bf16 bf16x8;
typedef __attribute__((ext_vector_type(4))) __bf16 bf16x4;
typedef __attribute__((ext_vector_type(4))) _Float16 f16x4;
typedef __attribute__((ext_vector_type(4))) float f32x4;

__device__ __forceinline__ f32x4 mfma16(bf16x8 a, bf16x8 b, f32x4 c) {
  return __builtin_amdgcn_mfma_f32_16x16x32_bf16(a, b, c, 0, 0, 0);
}
__device__ __forceinline__ float sigm(float x) { return 1.0f / (1.0f + __expf(-x)); }
__device__ __forceinline__ float tanh_fast(float x) {
  float e = __expf(2.0f * x);
  return 1.0f - 2.0f / (e + 1.0f);
}

// ---------------------------------------------------------------------------
// K0: weights -> bf16 in ws.
// ---------------------------------------------------------------------------
__global__ __launch_bounds__(256) void k_prep(
    const float* __restrict__ wpi, const float* __restrict__ wihh,
    const float* __restrict__ whhh, const float* __restrict__ wihw,
    const float* __restrict__ whhw, const float* __restrict__ wg,
    const float* __restrict__ wpo, bf16* __restrict__ dst) {
  int i = blockIdx.x * 256 + threadIdx.x;
  if (i < 49152) dst[i] = (bf16)wpi[i];
  else if (i < 98304) dst[i] = (bf16)wihh[i - 49152];
  else if (i < 147456) dst[i] = (bf16)whhh[i - 98304];
  else if (i < 196608) dst[i] = (bf16)wihw[i - 147456];
  else if (i < 245760) dst[i] = (bf16)whhw[i - 196608];
  else if (i < 262144) dst[i] = (bf16)wg[i - 245760];
  else if (i < 278528) dst[i] = (bf16)wpo[i - 262144];
}

// ---------------------------------------------------------------------------
// K1: per (b,h) row: resize+concat [64w][384c] in LDS, proj_in GEMM, BN+ReLU.
// Writes xf16 [b][c][h][w] (residual), xb [p][c] bf16, xbT [b,w,h][c] bf16.
// ---------------------------------------------------------------------------
__global__ __launch_bounds__(256, 2) void k_projin(
    const float* __restrict__ lp, const float* __restrict__ mp,
    const float* __restrict__ sp, const float* __restrict__ pscale,
    const float* __restrict__ pshift, const bf16* __restrict__ Wpi,
    f16* __restrict__ xf16, bf16* __restrict__ xb, bf16* __restrict__ xbT) {
  __shared__ __align__(16) bf16 xin[64][392];
  const int tid = threadIdx.x;
  const int bb = blockIdx.x >> 6;
  const int h = blockIdx.x & 63;

  {  // ---- phase A: resize + concat into LDS ----
    const int wq = tid & 63, cq = tid >> 6;
    float wy[4]; int iy[4];
    {
      float ssum = 0.f;
#pragma unroll
      for (int dy = 0; dy < 4; ++dy) {
        int y = 2 * h - 1 + dy;
        bool ok = (y >= 0) && (y < 128);
        iy[dy] = ok ? y : 0;
        float w0 = (dy == 0 || dy == 3) ? 0.125f : 0.375f;
        wy[dy] = ok ? w0 : 0.f;
        ssum += wy[dy];
      }
      float inv = 1.f / ssum;
#pragma unroll
      for (int dy = 0; dy < 4; ++dy) wy[dy] *= inv;
    }
    float wx[4]; int ix[4];
    {
      float ssum = 0.f;
#pragma unroll
      for (int dx = 0; dx < 4; ++dx) {
        int xq = 2 * wq - 1 + dx;
        bool ok = (xq >= 0) && (xq < 128);
        ix[dx] = ok ? xq : 0;
        float w0 = (dx == 0 || dx == 3) ? 0.125f : 0.375f;
        wx[dx] = ok ? w0 : 0.f;
        ssum += wx[dx];
      }
      float inv = 1.f / ssum;
#pragma unroll
      for (int dx = 0; dx < 4; ++dx) wx[dx] *= inv;
    }
    int syA, syB; float wsyA, wsyB;
    {
      int j0 = (h - 1) >> 1;
      float f = (h & 1) ? 0.25f : 0.75f;
      float a = 1.f - f, b2 = f;
      if (j0 < 0) a = 0.f;
      if (j0 + 1 > 31) b2 = 0.f;
      float inv = 1.f / (a + b2);
      wsyA = a * inv; wsyB = b2 * inv;
      syA = j0 < 0 ? 0 : j0;
      syB = (j0 + 1 > 31) ? 31 : (j0 + 1);
    }
    int sxA, sxB; float wsxA, wsxB;
    {
      int j0 = (wq - 1) >> 1;
      float f = (wq & 1) ? 0.25f : 0.75f;
      float a = 1.f - f, b2 = f;
      if (j0 < 0) a = 0.f;
      if (j0 + 1 > 31) b2 = 0.f;
      float inv = 1.f / (a + b2);
      wsxA = a * inv; wsxB = b2 * inv;
      sxA = j0 < 0 ? 0 : j0;
      sxB = (j0 + 1 > 31) ? 31 : (j0 + 1);
    }
    for (int ci = 0; ci < 32; ++ci) {
      int c = cq * 32 + ci;
      const float* lc = lp + ((size_t)(bb * 128 + c) << 14);
      float acc = 0.f;
#pragma unroll
      for (int dy = 0; dy < 4; ++dy) {
        const float* row = lc + (iy[dy] << 7);
        float rs = wx[0] * row[ix[0]] + wx[1] * row[ix[1]] +
                   wx[2] * row[ix[2]] + wx[3] * row[ix[3]];
        acc = fmaf(wy[dy], rs, acc);
      }
      xin[wq][c] = (bf16)acc;
      xin[wq][128 + c] = (bf16)mp[((bb * 128 + c) * 64 + h) * 64 + wq];
      const float* sc = sp + ((size_t)(bb * 128 + c) << 10);
      float sv = wsyA * (wsxA * sc[(syA << 5) + sxA] + wsxB * sc[(syA << 5) + sxB]) +
                 wsyB * (wsxA * sc[(syB << 5) + sxA] + wsxB * sc[(syB << 5) + sxB]);
      xin[wq][256 + c] = (bf16)sv;
    }
  }
  __syncthreads();

  // ---- phase B: MFMA proj_in (M=128 out-ch, N=64 w, K=384) ----
  const int lane = tid & 63, wv = tid >> 6;
  const int l16 = lane & 15, k8 = (lane >> 4) * 8, j4 = (lane >> 4) * 4;
  const f32x4 zf = {0.f, 0.f, 0.f, 0.f};
  f32x4 acc[2][4];
#pragma unroll
  for (int i = 0; i < 2; ++i)
#pragma unroll
    for (int pt = 0; pt < 4; ++pt) acc[i][pt] = zf;

  for (int kk = 0; kk < 12; ++kk) {
    bf16x8 bfr[4];
#pragma unroll
    for (int pt = 0; pt < 4; ++pt)
      bfr[pt] = *(const bf16x8*)&xin[pt * 16 + l16][kk * 32 + k8];
#pragma unroll
    for (int i = 0; i < 2; ++i) {
      bf16x8 afr = *(const bf16x8*)(Wpi + (size_t)((wv * 2 + i) * 16 + l16) * 384 + kk * 32 + k8);
#pragma unroll
      for (int pt = 0; pt < 4; ++pt) acc[i][pt] = mfma16(afr, bfr[pt], acc[i][pt]);
    }
  }
#pragma unroll
  for (int i = 0; i < 2; ++i) {
    int c0 = (wv * 2 + i) * 16 + j4;
    f32x4 scv = *(const f32x4*)&pscale[c0];
    f32x4 shv = *(const f32x4*)&pshift[c0];
#pragma unroll
    for (int pt = 0; pt < 4; ++pt) {
      int pw = pt * 16 + l16;
      bf16x4 pk;
      f16x4 pf;
#pragma unroll
      for (int j = 0; j < 4; ++j) {
        float v = fmaxf(acc[i][pt][j] * scv[j] + shv[j], 0.f);
        xf16[(size_t)((bb * 128 + c0 + j) * 64 + h) * 64 + pw] = (f16)v;
        pk[j] = (bf16)v;
        pf[j] = (f16)v;
      }
      *(bf16x4*)&xb[(size_t)(bb * 4096 + h * 64 + pw) * 128 + c0] = pk;
      *(bf16x4*)&xbT[(size_t)(bb * 4096 + pw * 64 + h) * 128 + c0] = pk;
    }
  }
}

// ---------------------------------------------------------------------------
// K2: gx = x*wih^T + bih (+bhh for r,z) in scan-fragment layout:
//   gx[t][nb][part 0..2][tid 0..511][4] f16, part = r|z|n.
// Wave w owns gate rows {w*16, 128+w*16, 256+w*16}; lane (l16,hi) -> row
// n=nb*16+l16, channels w*16+hi*4+0..3.  Block = (2 t-values) x (16 n-rows).
// ---------------------------------------------------------------------------
__global__ __launch_bounds__(512, 2) void k_gx(
    const bf16* __restrict__ xb, const bf16* __restrict__ xbT,
    const bf16* __restrict__ wih_h_b, const bf16* __restrict__ wih_w_b,
    const float* __restrict__ bih_h, const float* __restrict__ bih_w,
    const float* __restrict__ bhh_h, const float* __restrict__ bhh_w,
    f16* __restrict__ gxh, f16* __restrict__ gxw) {
  const int dir = blockIdx.z;
  const int nb = blockIdx.y;
  const int t0 = blockIdx.x * 2;
  const bf16* xsrc = dir ? xbT : xb;
  const bf16* wih = dir ? wih_w_b : wih_h_b;
  const float* bih = dir ? bih_w : bih_h;
  const float* bhh = dir ? bhh_w : bhh_h;
  f16* gx = dir ? gxw : gxh;

  const int tid = threadIdx.x, lane = tid & 63, w = tid >> 6;
  const int l16 = lane & 15, k8 = (lane >> 4) * 8, j4 = (lane >> 4) * 4;
  const int n = nb * 16 + l16;
  const int pb = n >> 6, q = n & 63;

  bf16x8 afr[3][4];
#pragma unroll
  for (int part = 0; part < 3; ++part) {
    int gbase = part * 128 + w * 16;
#pragma unroll
    for (int kk = 0; kk < 4; ++kk)
      afr[part][kk] = *(const bf16x8*)(wih + (size_t)(gbase + l16) * 128 + kk * 32 + k8);
  }
  const f32x4 zf = {0.f, 0.f, 0.f, 0.f};
  f32x4 acc[3][2];
#pragma unroll
  for (int part = 0; part < 3; ++part) { acc[part][0] = zf; acc[part][1] = zf; }

#pragma unroll
  for (int pt = 0; pt < 2; ++pt) {
    const bf16* xr = xsrc + (size_t)(pb * 4096 + (t0 + pt) * 64 + q) * 128;
#pragma unroll
    for (int kk = 0; kk < 4; ++kk) {
      bf16x8 bfr = *(const bf16x8*)(xr + kk * 32 + k8);
#pragma unroll
      for (int part = 0; part < 3; ++part)
        acc[part][pt] = mfma16(afr[part][kk], bfr, acc[part][pt]);
    }
  }
#pragma unroll
  for (int part = 0; part < 3; ++part) {
    int g0 = part * 128 + w * 16 + j4;
    f32x4 bi = *(const f32x4*)&bih[g0];
    if (part < 2) {
      f32x4 bh = *(const f32x4*)&bhh[g0];
#pragma unroll
      for (int j = 0; j < 4; ++j) bi[j] += bh[j];
    }
#pragma unroll
    for (int pt = 0; pt < 2; ++pt) {
      f16x4 pk;
#pragma unroll
      for (int j = 0; j < 4; ++j) pk[j] = (f16)(acc[part][pt][j] + bi[j]);
      *(f16x4*)&gx[((size_t)(((t0 + pt) * 32 + nb) * 3 + part) * 512 + tid) * 4] = pk;
    }
  }
}

// ---------------------------------------------------------------------------
// K3: GRU scans. 64 blocks x 512 threads (8 waves, 2/SIMD).
// Per block: 16 batch-rows, 64 serial steps. Wave w owns gate rows
// {w*16, 128+w*16, 256+w*16}; h state in registers (f32x4/lane);
// double-buffered bf16 h tile in LDS; ONE barrier per step; gx prefetched.
// ---------------------------------------------------------------------------
__global__ __launch_bounds__(512, 2) void k_scan(
    const bf16* __restrict__ whh_h_b, const bf16* __restrict__ whh_w_b,
    const float* __restrict__ bhh_h, const float* __restrict__ bhh_w,
    const f16* __restrict__ gxh, const f16* __restrict__ gxw,
    f16* __restrict__ ohb, f16* __restrict__ owb) {
  const int dir = blockIdx.x >> 5;
  const int nb = blockIdx.x & 31;
  const int nbase = nb * 16;
  const bf16* whh = dir ? whh_w_b : whh_h_b;
  const float* bhh = dir ? bhh_w : bhh_h;
  const f16* gx = dir ? gxw : gxh;
  f16* outb = dir ? owb : ohb;

  __shared__ __align__(16) bf16 hbuf[2][16][136];  // stride 136: 2-way bank alias only

  const int tid = threadIdx.x, lane = tid & 63, w = tid >> 6;
  const int l16 = lane & 15, k8 = (lane >> 4) * 8, j4 = (lane >> 4) * 4;
  const int cc0 = w * 16 + j4;  // this lane's 4 channels

  // hoist whh fragments (12 x bf16x8 = 48 VGPR)
  bf16x8 afr[3][4];
#pragma unroll
  for (int part = 0; part < 3; ++part) {
    int gbase = part * 128 + w * 16;
#pragma unroll
    for (int kk = 0; kk < 4; ++kk)
      afr[part][kk] = *(const bf16x8*)(whh + (size_t)(gbase + l16) * 128 + kk * 32 + k8);
  }
  const f32x4 bhn = *(const f32x4*)&bhh[256 + cc0];

  // zero h buffer 0 (cols 0..127 used; zero all incl. pad)
  for (int i = tid; i < 2 * 16 * 136; i += 512) ((bf16*)hbuf)[i] = (bf16)0.f;

  const int n = nbase + l16;
  const int pb = n >> 6, q = n & 63;
  const int pbase0 = pb * 4096 + (dir ? q * 64 : q);
  const int pstep = dir ? 1 : 64;

  // preload gx for t=0
  f16x4 gxr, gxz, gxn;
  {
    const size_t b0 = ((size_t)(0 * 32 + nb) * 3) * 512 + tid;
    gxr = *(const f16x4*)&gx[(b0) * 4];
    gxz = *(const f16x4*)&gx[(b0 + 512) * 4];
    gxn = *(const f16x4*)&gx[(b0 + 1024) * 4];
  }
  f32x4 hreg = {0.f, 0.f, 0.f, 0.f};
  int cur = 0;
  __syncthreads();

  const f32x4 zf = {0.f, 0.f, 0.f, 0.f};
  for (int t = 0; t < 64; ++t) {
    // B-fragment: h rows from LDS
    bf16x8 hb[4];
#pragma unroll
    for (int kk = 0; kk < 4; ++kk)
      hb[kk] = *(const bf16x8*)&hbuf[cur][l16][kk * 32 + k8];
    // prefetch gx for t+1 (consumed next iteration -> full step of slack)
    f16x4 gxr_n, gxz_n, gxn_n;
    {
      int tn = t < 63 ? t + 1 : 63;
      const size_t b0 = ((size_t)(tn * 32 + nb) * 3) * 512 + tid;
      gxr_n = *(const f16x4*)&gx[(b0) * 4];
      gxz_n = *(const f16x4*)&gx[(b0 + 512) * 4];
      gxn_n = *(const f16x4*)&gx[(b0 + 1024) * 4];
    }
    // gh = h @ whh^T for this wave's 3 gate tiles
    f32x4 aR = zf, aZ = zf, aN = zf;
#pragma unroll
    for (int kk = 0; kk < 4; ++kk) {
      aR = mfma16(afr[0][kk], hb[kk], aR);
      aZ = mfma16(afr[1][kk], hb[kk], aZ);
      aN = mfma16(afr[2][kk], hb[kk], aN);
    }
    // gates + state update, all in registers
    bf16x4 hb4;
    f16x4 o4;
#pragma unroll
    for (int j = 0; j < 4; ++j) {
      float r = sigm((float)gxr[j] + aR[j]);
      float z = sigm((float)gxz[j] + aZ[j]);
      float nn = tanh_fast((float)gxn[j] + r * (aN[j] + bhn[j]));
      float h = nn + z * (hreg[j] - nn);
      hreg[j] = h;
      hb4[j] = (bf16)h;
      o4[j] = (f16)h;
    }
    *(bf16x4*)&hbuf[cur ^ 1][l16][cc0] = hb4;
    *(f16x4*)&outb[(size_t)(pbase0 + t * pstep) * 128 + cc0] = o4;
    __syncthreads();
    cur ^= 1;
    gxr = gxr_n; gxz = gxz_n; gxn = gxn_n;
  }
}

// ---------------------------------------------------------------------------
// K4: scanned = oh+ow; gate = sigmoid(scanned@gate_w^T+b); gated = scanned*gate;
// out = relu(gated@proj_out^T * scale + shift) + x.  One (b,h) row per block.
// ---------------------------------------------------------------------------
__global__ __launch_bounds__(256, 2) void k_final(
    const f16* __restrict__ ohb, const f16* __restrict__ owb,
    const bf16* __restrict__ Wg, const float* __restrict__ gate_b,
    const bf16* __restrict__ Wpo, const float* __restrict__ poscale,
    const float* __restrict__ poshift, const f16* __restrict__ xf16,
    float* __restrict__ out) {
  __shared__ __align__(16) float sf[64][132];
  __shared__ __align__(16) bf16 sb[64][136];
  __shared__ __align__(16) bf16 gbuf[64][136];
  const int tid = threadIdx.x;
  const int bb = blockIdx.x >> 6, h = blockIdx.x & 63;
  const int pbase = bb * 4096 + h * 64;
  for (int i = tid; i < 8192; i += 256) {
    int w = i >> 7, cc = i & 127;
    size_t idx = (size_t)(pbase + w) * 128 + cc;
    float v = (float)ohb[idx] + (float)owb[idx];
    sf[w][cc] = v;
    sb[w][cc] = (bf16)v;
  }
  __syncthreads();
  const int lane = tid & 63, wv = tid >> 6;
  const int l16 = lane & 15, k8 = (lane >> 4) * 8, j4 = (lane >> 4) * 4;
  const f32x4 zf = {0.f, 0.f, 0.f, 0.f};
  f32x4 acc[2][4];
#pragma unroll
  for (int i = 0; i < 2; ++i)
#pragma unroll
    for (int pt = 0; pt < 4; ++pt) acc[i][pt] = zf;
#pragma unroll
  for (int kk = 0; kk < 4; ++kk) {
    bf16x8 bfr[4];
#pragma unroll
    for (int pt = 0; pt < 4; ++pt)
      bfr[pt] = *(const bf16x8*)&sb[pt * 16 + l16][kk * 32 + k8];
#pragma unroll
    for (int i = 0; i < 2; ++i) {
      bf16x8 afr = *(const bf16x8*)(Wg + (size_t)((wv * 2 + i) * 16 + l16) * 128 + kk * 32 + k8);
#pragma unroll
      for (int pt = 0; pt < 4; ++pt) acc[i][pt] = mfma16(afr, bfr[pt], acc[i][pt]);
    }
  }
#pragma unroll
  for (int i = 0; i < 2; ++i) {
    int o0 = (wv * 2 + i) * 16 + j4;
    f32x4 gb4 = *(const f32x4*)&gate_b[o0];
#pragma unroll
    for (int pt = 0; pt < 4; ++pt) {
      int pc = pt * 16 + l16;
      f32x4 sv = *(const f32x4*)&sf[pc][o0];
      bf16x4 pk;
#pragma unroll
      for (int j = 0; j < 4; ++j) {
        float g = sigm(acc[i][pt][j] + gb4[j]);
        pk[j] = (bf16)(sv[j] * g);
      }
      *(bf16x4*)&gbuf[pc][o0] = pk;
    }
  }
  __syncthreads();
  f32x4 acc2[2][4];
#pragma unroll
  for (int i = 0; i < 2; ++i)
#pragma unroll
    for (int pt = 0; pt < 4; ++pt) acc2[i][pt] = zf;
#pragma unroll
  for (int kk = 0; kk < 4; ++kk) {
    bf16x8 bfr[4];
#pragma unroll
    for (int pt = 0; pt < 4; ++pt)
      bfr[pt] = *(const bf16x8*)&gbuf[pt * 16 + l16][kk * 32 + k8];
#pragma unroll
    for (int i = 0; i < 2; ++i) {
      bf16x8 afr = *(const bf16x8*)(Wpo + (size_t)((wv * 2 + i) * 16 + l16) * 128 + kk * 32 + k8);
#pragma unroll
      for (int pt = 0; pt < 4; ++pt) acc2[i][pt] = mfma16(afr, bfr[pt], acc2[i][pt]);
    }
  }
#pragma unroll
  for (int i = 0; i < 2; ++i) {
    int o0 = (wv * 2 + i) * 16 + j4;
    f32x4 scv = *(const f32x4*)&poscale[o0];
    f32x4 shv = *(const f32x4*)&poshift[o0];
#pragma unroll
    for (int pt = 0; pt < 4; ++pt) {
      int pc = pt * 16 + l16;
#pragma unroll
      for (int j = 0; j < 4; ++j) {
        int oc = o0 + j;
        size_t oi = (size_t)((bb * 128 + oc) * 64 + h) * 64 + pc;
        float v = fmaxf(acc2[i][pt][j] * scv[j] + shv[j], 0.f) + (float)xf16[oi];
        out[oi] = v;
      }
    }
  }
}

// ---------------------------------------------------------------------------
// ws layout (bytes), total 92,831,744:
//   [0,        557056)     weights bf16
//   [557056,   8945664)    x f16  [b][c][h][w]   (residual)
//   [8945664,  17334272)   xb bf16 [b,h,w][c]
//   [17334272, 25722880)   xbT bf16 [b,w,h][c]
//   [25722880, 50888704)   gx_h f16 [t][nb][3][512][4]
//   [50888704, 76054528)   gx_w f16
//   [76054528, 84443136)   oh f16 [p][c]
//   [84443136, 92831744)   ow f16
// ---------------------------------------------------------------------------
extern "C" void kernel_launch(void* const* d_in, const int* in_sizes, int n_in,
                              void* d_out, int out_size, void* d_ws, size_t ws_size,
                              hipStream_t stream) {
  const float* lp = (const float*)d_in[0];
  const float* mp = (const float*)d_in[1];
  const float* sp = (const float*)d_in[2];
  const float* proj_in_w = (const float*)d_in[3];
  const float* proj_in_scale = (const float*)d_in[4];
  const float* proj_in_shift = (const float*)d_in[5];
  const float* wih_h = (const float*)d_in[6];
  const float* whh_h = (const float*)d_in[7];
  const float* bih_h = (const float*)d_in[8];
  const float* bhh_h = (const float*)d_in[9];
  const float* wih_w = (const float*)d_in[10];
  const float* whh_w = (const float*)d_in[11];
  const float* bih_w = (const float*)d_in[12];
  const float* bhh_w = (const float*)d_in[13];
  const float* gate_w = (const float*)d_in[14];
  const float* gate_b = (const float*)d_in[15];
  const float* proj_out_w = (const float*)d_in[16];
  const float* proj_out_scale = (const float*)d_in[17];
  const float* proj_out_shift = (const float*)d_in[18];
  float* out = (float*)d_out;

  char* ws = (char*)d_ws;
  bf16* wb = (bf16*)ws;
  bf16* Wpi_b = wb + 0;
  bf16* Wih_h_b = wb + 49152;
  bf16* Whh_h_b = wb + 98304;
  bf16* Wih_w_b = wb + 147456;
  bf16* Whh_w_b = wb + 196608;
  bf16* Wg_b = wb + 245760;
  bf16* Wpo_b = wb + 262144;
  f16* xf16 = (f16*)(ws + 557056);
  bf16* xb = (bf16*)(ws + 8945664);
  bf16* xbT = (bf16*)(ws + 17334272);
  f16* gxh = (f16*)(ws + 25722880);
  f16* gxw = (f16*)(ws + 50888704);
  f16* ohb = (f16*)(ws + 76054528);
  f16* owb = (f16*)(ws + 84443136);

  k_prep<<<dim3(1088), dim3(256), 0, stream>>>(proj_in_w, wih_h, whh_h, wih_w,
                                               whh_w, gate_w, proj_out_w, wb);
  k_projin<<<dim3(512), dim3(256), 0, stream>>>(lp, mp, sp, proj_in_scale,
                                                proj_in_shift, Wpi_b, xf16, xb, xbT);
  k_gx<<<dim3(32, 32, 2), dim3(512), 0, stream>>>(xb, xbT, Wih_h_b, Wih_w_b,
                                                  bih_h, bih_w, bhh_h, bhh_w,
                                                  gxh, gxw);
  k_scan<<<dim3(64), dim3(512), 0, stream>>>(Whh_h_b, Whh_w_b, bhh_h, bhh_w,
                                             gxh, gxw, ohb, owb);
  k_final<<<dim3(512), dim3(256), 0, stream>>>(ohb, owb, Wg_b, gate_b, Wpo_b,
                                               proj_out_scale, proj_out_shift,
                                               xf16, out);
}

// Round 3
// 292.967 us; speedup vs baseline: 1.3697x; 1.0555x over previous
//
#include <hip/hip_runtime.h>

// ---------------------------------------------------------------------------
// CrossScaleSelectiveScan: resize+concat+proj_in -> dual GRU scans -> gate+proj_out
// B=8, C=128, H=W=64.  All GEMMs via v_mfma_f32_16x16x32_bf16.
// R2: (a) k_scan: raw s_barrier + lgkmcnt(0) only (no vmcnt drain per step;
//         gx prefetch loads + output stores stay in flight across steps).
//     (b) k_projin: l-downsample via coalesced float2 + shfl taps (halves l
//         HBM traffic), 512-thread blocks.
// ---------------------------------------------------------------------------

typedef __bf16 bf16;
typedef _Float16 f16;
typedef __attribute__((ext_vector_type(8))) __bf16 bf16x8;
typedef __attribute__((ext_vector_type(4))) __bf16 bf16x4;
typedef __attribute__((ext_vector_type(4))) _Float16 f16x4;
typedef __attribute__((ext_vector_type(4))) float f32x4;
typedef __attribute__((ext_vector_type(2))) float f32x2;

__device__ __forceinline__ f32x4 mfma16(bf16x8 a, bf16x8 b, f32x4 c) {
  return __builtin_amdgcn_mfma_f32_16x16x32_bf16(a, b, c, 0, 0, 0);
}
__device__ __forceinline__ float sigm(float x) { return 1.0f / (1.0f + __expf(-x)); }
__device__ __forceinline__ float tanh_fast(float x) {
  float e = __expf(2.0f * x);
  return 1.0f - 2.0f / (e + 1.0f);
}

// ---------------------------------------------------------------------------
// K0: weights -> bf16 in ws.
// ---------------------------------------------------------------------------
__global__ __launch_bounds__(256) void k_prep(
    const float* __restrict__ wpi, const float* __restrict__ wihh,
    const float* __restrict__ whhh, const float* __restrict__ wihw,
    const float* __restrict__ whhw, const float* __restrict__ wg,
    const float* __restrict__ wpo, bf16* __restrict__ dst) {
  int i = blockIdx.x * 256 + threadIdx.x;
  if (i < 49152) dst[i] = (bf16)wpi[i];
  else if (i < 98304) dst[i] = (bf16)wihh[i - 49152];
  else if (i < 147456) dst[i] = (bf16)whhh[i - 98304];
  else if (i < 196608) dst[i] = (bf16)wihw[i - 147456];
  else if (i < 245760) dst[i] = (bf16)whhw[i - 196608];
  else if (i < 262144) dst[i] = (bf16)wg[i - 245760];
  else if (i < 278528) dst[i] = (bf16)wpo[i - 262144];
}

// ---------------------------------------------------------------------------
// K1: per (b,h) row: resize+concat [64w][384c] in LDS, proj_in GEMM, BN+ReLU.
// 512 threads. l-downsample: lane w loads float2 at col 2w (coalesced),
// neighbor taps via shfl (edge taps have weight 0).
// Writes xf16 [b][c][h][w] (residual), xb [p][c] bf16, xbT [b,w,h][c] bf16.
// ---------------------------------------------------------------------------
__global__ __launch_bounds__(512, 2) void k_projin(
    const float* __restrict__ lp, const float* __restrict__ mp,
    const float* __restrict__ sp, const float* __restrict__ pscale,
    const float* __restrict__ pshift, const bf16* __restrict__ Wpi,
    f16* __restrict__ xf16, bf16* __restrict__ xb, bf16* __restrict__ xbT) {
  __shared__ __align__(16) bf16 xin[64][392];
  const int tid = threadIdx.x;
  const int bb = blockIdx.x >> 6;
  const int h = blockIdx.x & 63;

  {  // ---- phase A: resize + concat into LDS ----
    const int wq = tid & 63, cq = tid >> 6;  // cq in 0..7
    // vertical taps for l (128->64 rows)
    float wy[4]; int iy[4];
    {
      float ssum = 0.f;
#pragma unroll
      for (int dy = 0; dy < 4; ++dy) {
        int y = 2 * h - 1 + dy;
        bool ok = (y >= 0) && (y < 128);
        iy[dy] = ok ? y : 0;
        float w0 = (dy == 0 || dy == 3) ? 0.125f : 0.375f;
        wy[dy] = ok ? w0 : 0.f;
        ssum += wy[dy];
      }
      float inv = 1.f / ssum;
#pragma unroll
      for (int dy = 0; dy < 4; ++dy) wy[dy] *= inv;
    }
    // horizontal taps for l: out col wq uses 2wq-1..2wq+2
    float wx[4];
    {
      float ssum = 0.f;
#pragma unroll
      for (int dx = 0; dx < 4; ++dx) {
        int xq = 2 * wq - 1 + dx;
        bool ok = (xq >= 0) && (xq < 128);
        float w0 = (dx == 0 || dx == 3) ? 0.125f : 0.375f;
        wx[dx] = ok ? w0 : 0.f;
        ssum += wx[dx];
      }
      float inv = 1.f / ssum;
#pragma unroll
      for (int dx = 0; dx < 4; ++dx) wx[dx] *= inv;
    }
    // s upsample (32->64)
    int syA, syB; float wsyA, wsyB;
    {
      int j0 = (h - 1) >> 1;
      float f = (h & 1) ? 0.25f : 0.75f;
      float a = 1.f - f, b2 = f;
      if (j0 < 0) a = 0.f;
      if (j0 + 1 > 31) b2 = 0.f;
      float inv = 1.f / (a + b2);
      wsyA = a * inv; wsyB = b2 * inv;
      syA = j0 < 0 ? 0 : j0;
      syB = (j0 + 1 > 31) ? 31 : (j0 + 1);
    }
    int sxA, sxB; float wsxA, wsxB;
    {
      int j0 = (wq - 1) >> 1;
      float f = (wq & 1) ? 0.25f : 0.75f;
      float a = 1.f - f, b2 = f;
      if (j0 < 0) a = 0.f;
      if (j0 + 1 > 31) b2 = 0.f;
      float inv = 1.f / (a + b2);
      wsxA = a * inv; wsxB = b2 * inv;
      sxA = j0 < 0 ? 0 : j0;
      sxB = (j0 + 1 > 31) ? 31 : (j0 + 1);
    }
#pragma unroll 4
    for (int ci = 0; ci < 16; ++ci) {
      int c = cq * 16 + ci;
      const float* lc = lp + ((size_t)(bb * 128 + c) << 14);
      float acc = 0.f;
#pragma unroll
      for (int dy = 0; dy < 4; ++dy) {
        const float* row = lc + (iy[dy] << 7);
        f32x2 v = *(const f32x2*)&row[2 * wq];  // cols 2w, 2w+1 (coalesced)
        float bprev = __shfl_up(v.y, 1);        // col 2w-1
        float anext = __shfl_down(v.x, 1);      // col 2w+2
        float rs = wx[0] * bprev + wx[1] * v.x + wx[2] * v.y + wx[3] * anext;
        acc = fmaf(wy[dy], rs, acc);
      }
      xin[wq][c] = (bf16)acc;
      xin[wq][128 + c] = (bf16)mp[((bb * 128 + c) * 64 + h) * 64 + wq];
      const float* sc = sp + ((size_t)(bb * 128 + c) << 10);
      float sv = wsyA * (wsxA * sc[(syA << 5) + sxA] + wsxB * sc[(syA << 5) + sxB]) +
                 wsyB * (wsxA * sc[(syB << 5) + sxA] + wsxB * sc[(syB << 5) + sxB]);
      xin[wq][256 + c] = (bf16)sv;
    }
  }
  __syncthreads();

  // ---- phase B: MFMA proj_in (M=128 out-ch over 8 waves, N=64 w, K=384) ----
  const int lane = tid & 63, wv = tid >> 6;
  const int l16 = lane & 15, k8 = (lane >> 4) * 8, j4 = (lane >> 4) * 4;
  const f32x4 zf = {0.f, 0.f, 0.f, 0.f};
  f32x4 acc[4];
#pragma unroll
  for (int pt = 0; pt < 4; ++pt) acc[pt] = zf;

  for (int kk = 0; kk < 12; ++kk) {
    bf16x8 bfr[4];
#pragma unroll
    for (int pt = 0; pt < 4; ++pt)
      bfr[pt] = *(const bf16x8*)&xin[pt * 16 + l16][kk * 32 + k8];
    bf16x8 afr = *(const bf16x8*)(Wpi + (size_t)(wv * 16 + l16) * 384 + kk * 32 + k8);
#pragma unroll
    for (int pt = 0; pt < 4; ++pt) acc[pt] = mfma16(afr, bfr[pt], acc[pt]);
  }
  {
    int c0 = wv * 16 + j4;
    f32x4 scv = *(const f32x4*)&pscale[c0];
    f32x4 shv = *(const f32x4*)&pshift[c0];
#pragma unroll
    for (int pt = 0; pt < 4; ++pt) {
      int pw = pt * 16 + l16;
      bf16x4 pk;
#pragma unroll
      for (int j = 0; j < 4; ++j) {
        float v = fmaxf(acc[pt][j] * scv[j] + shv[j], 0.f);
        xf16[(size_t)((bb * 128 + c0 + j) * 64 + h) * 64 + pw] = (f16)v;
        pk[j] = (bf16)v;
      }
      *(bf16x4*)&xb[(size_t)(bb * 4096 + h * 64 + pw) * 128 + c0] = pk;
      *(bf16x4*)&xbT[(size_t)(bb * 4096 + pw * 64 + h) * 128 + c0] = pk;
    }
  }
}

// ---------------------------------------------------------------------------
// K2: gx = x*wih^T + bih (+bhh for r,z) in scan-fragment layout:
//   gx[t][nb][part 0..2][tid 0..511][4] f16, part = r|z|n.
// ---------------------------------------------------------------------------
__global__ __launch_bounds__(512, 2) void k_gx(
    const bf16* __restrict__ xb, const bf16* __restrict__ xbT,
    const bf16* __restrict__ wih_h_b, const bf16* __restrict__ wih_w_b,
    const float* __restrict__ bih_h, const float* __restrict__ bih_w,
    const float* __restrict__ bhh_h, const float* __restrict__ bhh_w,
    f16* __restrict__ gxh, f16* __restrict__ gxw) {
  const int dir = blockIdx.z;
  const int nb = blockIdx.y;
  const int t0 = blockIdx.x * 2;
  const bf16* xsrc = dir ? xbT : xb;
  const bf16* wih = dir ? wih_w_b : wih_h_b;
  const float* bih = dir ? bih_w : bih_h;
  const float* bhh = dir ? bhh_w : bhh_h;
  f16* gx = dir ? gxw : gxh;

  const int tid = threadIdx.x, lane = tid & 63, w = tid >> 6;
  const int l16 = lane & 15, k8 = (lane >> 4) * 8, j4 = (lane >> 4) * 4;
  const int n = nb * 16 + l16;
  const int pb = n >> 6, q = n & 63;

  bf16x8 afr[3][4];
#pragma unroll
  for (int part = 0; part < 3; ++part) {
    int gbase = part * 128 + w * 16;
#pragma unroll
    for (int kk = 0; kk < 4; ++kk)
      afr[part][kk] = *(const bf16x8*)(wih + (size_t)(gbase + l16) * 128 + kk * 32 + k8);
  }
  const f32x4 zf = {0.f, 0.f, 0.f, 0.f};
  f32x4 acc[3][2];
#pragma unroll
  for (int part = 0; part < 3; ++part) { acc[part][0] = zf; acc[part][1] = zf; }

#pragma unroll
  for (int pt = 0; pt < 2; ++pt) {
    const bf16* xr = xsrc + (size_t)(pb * 4096 + (t0 + pt) * 64 + q) * 128;
#pragma unroll
    for (int kk = 0; kk < 4; ++kk) {
      bf16x8 bfr = *(const bf16x8*)(xr + kk * 32 + k8);
#pragma unroll
      for (int part = 0; part < 3; ++part)
        acc[part][pt] = mfma16(afr[part][kk], bfr, acc[part][pt]);
    }
  }
#pragma unroll
  for (int part = 0; part < 3; ++part) {
    int g0 = part * 128 + w * 16 + j4;
    f32x4 bi = *(const f32x4*)&bih[g0];
    if (part < 2) {
      f32x4 bh = *(const f32x4*)&bhh[g0];
#pragma unroll
      for (int j = 0; j < 4; ++j) bi[j] += bh[j];
    }
#pragma unroll
    for (int pt = 0; pt < 2; ++pt) {
      f16x4 pk;
#pragma unroll
      for (int j = 0; j < 4; ++j) pk[j] = (f16)(acc[part][pt][j] + bi[j]);
      *(f16x4*)&gx[((size_t)(((t0 + pt) * 32 + nb) * 3 + part) * 512 + tid) * 4] = pk;
    }
  }
}

// ---------------------------------------------------------------------------
// K3: GRU scans. 64 blocks x 512 threads (8 waves, 2/SIMD).
// Raw s_barrier + lgkmcnt(0) per step (LDS-only sync; gx loads and output
// stores stay in flight across the barrier).
// ---------------------------------------------------------------------------
__global__ __launch_bounds__(512, 2) void k_scan(
    const bf16* __restrict__ whh_h_b, const bf16* __restrict__ whh_w_b,
    const float* __restrict__ bhh_h, const float* __restrict__ bhh_w,
    const f16* __restrict__ gxh, const f16* __restrict__ gxw,
    f16* __restrict__ ohb, f16* __restrict__ owb) {
  const int dir = blockIdx.x >> 5;
  const int nb = blockIdx.x & 31;
  const bf16* whh = dir ? whh_w_b : whh_h_b;
  const float* bhh = dir ? bhh_w : bhh_h;
  const f16* gx = dir ? gxw : gxh;
  f16* outb = dir ? owb : ohb;

  __shared__ __align__(16) bf16 hbuf[2][16][136];

  const int tid = threadIdx.x, lane = tid & 63, w = tid >> 6;
  const int l16 = lane & 15, k8 = (lane >> 4) * 8, j4 = (lane >> 4) * 4;
  const int cc0 = w * 16 + j4;

  bf16x8 afr[3][4];
#pragma unroll
  for (int part = 0; part < 3; ++part) {
    int gbase = part * 128 + w * 16;
#pragma unroll
    for (int kk = 0; kk < 4; ++kk)
      afr[part][kk] = *(const bf16x8*)(whh + (size_t)(gbase + l16) * 128 + kk * 32 + k8);
  }
  const f32x4 bhn = *(const f32x4*)&bhh[256 + cc0];

  for (int i = tid; i < 2 * 16 * 136; i += 512) ((bf16*)hbuf)[i] = (bf16)0.f;

  const int n = nb * 16 + l16;
  const int pb = n >> 6, q = n & 63;
  const int pbase0 = pb * 4096 + (dir ? q * 64 : q);
  const int pstep = dir ? 1 : 64;

  // preload gx for t=0
  f16x4 gxr, gxz, gxn;
  {
    const size_t b0 = ((size_t)nb * 3) * 512 + tid;
    gxr = *(const f16x4*)&gx[(b0) * 4];
    gxz = *(const f16x4*)&gx[(b0 + 512) * 4];
    gxn = *(const f16x4*)&gx[(b0 + 1024) * 4];
  }
  f32x4 hreg = {0.f, 0.f, 0.f, 0.f};
  int cur = 0;
  __syncthreads();

  const f32x4 zf = {0.f, 0.f, 0.f, 0.f};
  for (int t = 0; t < 64; ++t) {
    // issue prefetch for t+1 first (max slack; consumed after next barrier)
    f16x4 gxr_n, gxz_n, gxn_n;
    {
      int tn = t < 63 ? t + 1 : 63;
      const size_t b0 = ((size_t)(tn * 32 + nb) * 3) * 512 + tid;
      gxr_n = *(const f16x4*)&gx[(b0) * 4];
      gxz_n = *(const f16x4*)&gx[(b0 + 512) * 4];
      gxn_n = *(const f16x4*)&gx[(b0 + 1024) * 4];
    }
    // B-fragment: h rows from LDS
    bf16x8 hb[4];
#pragma unroll
    for (int kk = 0; kk < 4; ++kk)
      hb[kk] = *(const bf16x8*)&hbuf[cur][l16][kk * 32 + k8];
    // gh = h @ whh^T for this wave's 3 gate tiles
    f32x4 aR = zf, aZ = zf, aN = zf;
#pragma unroll
    for (int kk = 0; kk < 4; ++kk) {
      aR = mfma16(afr[0][kk], hb[kk], aR);
      aZ = mfma16(afr[1][kk], hb[kk], aZ);
      aN = mfma16(afr[2][kk], hb[kk], aN);
    }
    // gates + state update, in registers
    bf16x4 hb4;
    f16x4 o4;
#pragma unroll
    for (int j = 0; j < 4; ++j) {
      float r = sigm((float)gxr[j] + aR[j]);
      float z = sigm((float)gxz[j] + aZ[j]);
      float nn = tanh_fast((float)gxn[j] + r * (aN[j] + bhn[j]));
      float h = nn + z * (hreg[j] - nn);
      hreg[j] = h;
      hb4[j] = (bf16)h;
      o4[j] = (f16)h;
    }
    *(bf16x4*)&hbuf[cur ^ 1][l16][cc0] = hb4;
    *(f16x4*)&outb[(size_t)(pbase0 + t * pstep) * 128 + cc0] = o4;
    // LDS-only barrier: ds_writes visible, vmem stays in flight
    asm volatile("s_waitcnt lgkmcnt(0)\n\ts_barrier" ::: "memory");
    cur ^= 1;
    gxr = gxr_n; gxz = gxz_n; gxn = gxn_n;
  }
}

// ---------------------------------------------------------------------------
// K4: scanned = oh+ow; gate = sigmoid(scanned@gate_w^T+b); gated = scanned*gate;
// out = relu(gated@proj_out^T * scale + shift) + x.  One (b,h) row per block.
// ---------------------------------------------------------------------------
__global__ __launch_bounds__(256, 2) void k_final(
    const f16* __restrict__ ohb, const f16* __restrict__ owb,
    const bf16* __restrict__ Wg, const float* __restrict__ gate_b,
    const bf16* __restrict__ Wpo, const float* __restrict__ poscale,
    const float* __restrict__ poshift, const f16* __restrict__ xf16,
    float* __restrict__ out) {
  __shared__ __align__(16) float sf[64][132];
  __shared__ __align__(16) bf16 sb[64][136];
  __shared__ __align__(16) bf16 gbuf[64][136];
  const int tid = threadIdx.x;
  const int bb = blockIdx.x >> 6, h = blockIdx.x & 63;
  const int pbase = bb * 4096 + h * 64;
  for (int i = tid; i < 8192; i += 256) {
    int w = i >> 7, cc = i & 127;
    size_t idx = (size_t)(pbase + w) * 128 + cc;
    float v = (float)ohb[idx] + (float)owb[idx];
    sf[w][cc] = v;
    sb[w][cc] = (bf16)v;
  }
  __syncthreads();
  const int lane = tid & 63, wv = tid >> 6;
  const int l16 = lane & 15, k8 = (lane >> 4) * 8, j4 = (lane >> 4) * 4;
  const f32x4 zf = {0.f, 0.f, 0.f, 0.f};
  f32x4 acc[2][4];
#pragma unroll
  for (int i = 0; i < 2; ++i)
#pragma unroll
    for (int pt = 0; pt < 4; ++pt) acc[i][pt] = zf;
#pragma unroll
  for (int kk = 0; kk < 4; ++kk) {
    bf16x8 bfr[4];
#pragma unroll
    for (int pt = 0; pt < 4; ++pt)
      bfr[pt] = *(const bf16x8*)&sb[pt * 16 + l16][kk * 32 + k8];
#pragma unroll
    for (int i = 0; i < 2; ++i) {
      bf16x8 afr = *(const bf16x8*)(Wg + (size_t)((wv * 2 + i) * 16 + l16) * 128 + kk * 32 + k8);
#pragma unroll
      for (int pt = 0; pt < 4; ++pt) acc[i][pt] = mfma16(afr, bfr[pt], acc[i][pt]);
    }
  }
#pragma unroll
  for (int i = 0; i < 2; ++i) {
    int o0 = (wv * 2 + i) * 16 + j4;
    f32x4 gb4 = *(const f32x4*)&gate_b[o0];
#pragma unroll
    for (int pt = 0; pt < 4; ++pt) {
      int pc = pt * 16 + l16;
      f32x4 sv = *(const f32x4*)&sf[pc][o0];
      bf16x4 pk;
#pragma unroll
      for (int j = 0; j < 4; ++j) {
        float g = sigm(acc[i][pt][j] + gb4[j]);
        pk[j] = (bf16)(sv[j] * g);
      }
      *(bf16x4*)&gbuf[pc][o0] = pk;
    }
  }
  __syncthreads();
  f32x4 acc2[2][4];
#pragma unroll
  for (int i = 0; i < 2; ++i)
#pragma unroll
    for (int pt = 0; pt < 4; ++pt) acc2[i][pt] = zf;
#pragma unroll
  for (int kk = 0; kk < 4; ++kk) {
    bf16x8 bfr[4];
#pragma unroll
    for (int pt = 0; pt < 4; ++pt)
      bfr[pt] = *(const bf16x8*)&gbuf[pt * 16 + l16][kk * 32 + k8];
#pragma unroll
    for (int i = 0; i < 2; ++i) {
      bf16x8 afr = *(const bf16x8*)(Wpo + (size_t)((wv * 2 + i) * 16 + l16) * 128 + kk * 32 + k8);
#pragma unroll
      for (int pt = 0; pt < 4; ++pt) acc2[i][pt] = mfma16(afr, bfr[pt], acc2[i][pt]);
    }
  }
#pragma unroll
  for (int i = 0; i < 2; ++i) {
    int o0 = (wv * 2 + i) * 16 + j4;
    f32x4 scv = *(const f32x4*)&poscale[o0];
    f32x4 shv = *(const f32x4*)&poshift[o0];
#pragma unroll
    for (int pt = 0; pt < 4; ++pt) {
      int pc = pt * 16 + l16;
#pragma unroll
      for (int j = 0; j < 4; ++j) {
        int oc = o0 + j;
        size_t oi = (size_t)((bb * 128 + oc) * 64 + h) * 64 + pc;
        float v = fmaxf(acc2[i][pt][j] * scv[j] + shv[j], 0.f) + (float)xf16[oi];
        out[oi] = v;
      }
    }
  }
}

// ---------------------------------------------------------------------------
// ws layout (bytes), total 92,831,744:
//   [0,        557056)     weights bf16
//   [557056,   8945664)    x f16  [b][c][h][w]   (residual)
//   [8945664,  17334272)   xb bf16 [b,h,w][c]
//   [17334272, 25722880)   xbT bf16 [b,w,h][c]
//   [25722880, 50888704)   gx_h f16 [t][nb][3][512][4]
//   [50888704, 76054528)   gx_w f16
//   [76054528, 84443136)   oh f16 [p][c]
//   [84443136, 92831744)   ow f16
// ---------------------------------------------------------------------------
extern "C" void kernel_launch(void* const* d_in, const int* in_sizes, int n_in,
                              void* d_out, int out_size, void* d_ws, size_t ws_size,
                              hipStream_t stream) {
  const float* lp = (const float*)d_in[0];
  const float* mp = (const float*)d_in[1];
  const float* sp = (const float*)d_in[2];
  const float* proj_in_w = (const float*)d_in[3];
  const float* proj_in_scale = (const float*)d_in[4];
  const float* proj_in_shift = (const float*)d_in[5];
  const float* wih_h = (const float*)d_in[6];
  const float* whh_h = (const float*)d_in[7];
  const float* bih_h = (const float*)d_in[8];
  const float* bhh_h = (const float*)d_in[9];
  const float* wih_w = (const float*)d_in[10];
  const float* whh_w = (const float*)d_in[11];
  const float* bih_w = (const float*)d_in[12];
  const float* bhh_w = (const float*)d_in[13];
  const float* gate_w = (const float*)d_in[14];
  const float* gate_b = (const float*)d_in[15];
  const float* proj_out_w = (const float*)d_in[16];
  const float* proj_out_scale = (const float*)d_in[17];
  const float* proj_out_shift = (const float*)d_in[18];
  float* out = (float*)d_out;

  char* ws = (char*)d_ws;
  bf16* wb = (bf16*)ws;
  bf16* Wpi_b = wb + 0;
  bf16* Wih_h_b = wb + 49152;
  bf16* Whh_h_b = wb + 98304;
  bf16* Wih_w_b = wb + 147456;
  bf16* Whh_w_b = wb + 196608;
  bf16* Wg_b = wb + 245760;
  bf16* Wpo_b = wb + 262144;
  f16* xf16 = (f16*)(ws + 557056);
  bf16* xb = (bf16*)(ws + 8945664);
  bf16* xbT = (bf16*)(ws + 17334272);
  f16* gxh = (f16*)(ws + 25722880);
  f16* gxw = (f16*)(ws + 50888704);
  f16* ohb = (f16*)(ws + 76054528);
  f16* owb = (f16*)(ws + 84443136);

  k_prep<<<dim3(1088), dim3(256), 0, stream>>>(proj_in_w, wih_h, whh_h, wih_w,
                                               whh_w, gate_w, proj_out_w, wb);
  k_projin<<<dim3(512), dim3(512), 0, stream>>>(lp, mp, sp, proj_in_scale,
                                                proj_in_shift, Wpi_b, xf16, xb, xbT);
  k_gx<<<dim3(32, 32, 2), dim3(512), 0, stream>>>(xb, xbT, Wih_h_b, Wih_w_b,
                                                  bih_h, bih_w, bhh_h, bhh_w,
                                                  gxh, gxw);
  k_scan<<<dim3(64), dim3(512), 0, stream>>>(Whh_h_b, Whh_w_b, bhh_h, bhh_w,
                                             gxh, gxw, ohb, owb);
  k_final<<<dim3(512), dim3(256), 0, stream>>>(ohb, owb, Wg_b, gate_b, Wpo_b,
                                               proj_out_scale, proj_out_shift,
                                               xf16, out);
}

// Round 4
// 287.907 us; speedup vs baseline: 1.3938x; 1.0176x over previous
//
#include <hip/hip_runtime.h>

// ---------------------------------------------------------------------------
// CrossScaleSelectiveScan: resize+concat+proj_in -> dual GRU scans -> gate+proj_out
// B=8, C=128, H=W=64.  All GEMMs via v_mfma_f32_16x16x32_bf16.
// R3: k_scan: raw s_barrier intrinsic + bare lgkmcnt(0) asm (NO memory clobber
//     -> no vmcnt drain), sched_barrier(0) fences; t-loop unrolled x4 with
//     static gq[4][3] prefetch ring at depth 2 (no register rotation).
//     k_final: f16x4-vectorized oh/ow reads.
// ---------------------------------------------------------------------------

typedef __bf16 bf16;
typedef _Float16 f16;
typedef __attribute__((ext_vector_type(8))) __bf16 bf16x8;
typedef __attribute__((ext_vector_type(4))) __bf16 bf16x4;
typedef __attribute__((ext_vector_type(4))) _Float16 f16x4;
typedef __attribute__((ext_vector_type(4))) float f32x4;
typedef __attribute__((ext_vector_type(2))) float f32x2;

__device__ __forceinline__ f32x4 mfma16(bf16x8 a, bf16x8 b, f32x4 c) {
  return __builtin_amdgcn_mfma_f32_16x16x32_bf16(a, b, c, 0, 0, 0);
}
__device__ __forceinline__ float sigm(float x) { return 1.0f / (1.0f + __expf(-x)); }
__device__ __forceinline__ float tanh_fast(float x) {
  float e = __expf(2.0f * x);
  return 1.0f - 2.0f / (e + 1.0f);
}

// ---------------------------------------------------------------------------
// K0: weights -> bf16 in ws.
// ---------------------------------------------------------------------------
__global__ __launch_bounds__(256) void k_prep(
    const float* __restrict__ wpi, const float* __restrict__ wihh,
    const float* __restrict__ whhh, const float* __restrict__ wihw,
    const float* __restrict__ whhw, const float* __restrict__ wg,
    const float* __restrict__ wpo, bf16* __restrict__ dst) {
  int i = blockIdx.x * 256 + threadIdx.x;
  if (i < 49152) dst[i] = (bf16)wpi[i];
  else if (i < 98304) dst[i] = (bf16)wihh[i - 49152];
  else if (i < 147456) dst[i] = (bf16)whhh[i - 98304];
  else if (i < 196608) dst[i] = (bf16)wihw[i - 147456];
  else if (i < 245760) dst[i] = (bf16)whhw[i - 196608];
  else if (i < 262144) dst[i] = (bf16)wg[i - 245760];
  else if (i < 278528) dst[i] = (bf16)wpo[i - 262144];
}

// ---------------------------------------------------------------------------
// K1: per (b,h) row: resize+concat [64w][384c] in LDS, proj_in GEMM, BN+ReLU.
// 512 threads. l-downsample: lane w loads float2 at col 2w (coalesced),
// neighbor taps via shfl (edge taps have weight 0).
// Writes xf16 [b][c][h][w] (residual), xb [p][c] bf16, xbT [b,w,h][c] bf16.
// ---------------------------------------------------------------------------
__global__ __launch_bounds__(512, 2) void k_projin(
    const float* __restrict__ lp, const float* __restrict__ mp,
    const float* __restrict__ sp, const float* __restrict__ pscale,
    const float* __restrict__ pshift, const bf16* __restrict__ Wpi,
    f16* __restrict__ xf16, bf16* __restrict__ xb, bf16* __restrict__ xbT) {
  __shared__ __align__(16) bf16 xin[64][392];
  const int tid = threadIdx.x;
  const int bb = blockIdx.x >> 6;
  const int h = blockIdx.x & 63;

  {  // ---- phase A: resize + concat into LDS ----
    const int wq = tid & 63, cq = tid >> 6;  // cq in 0..7
    float wy[4]; int iy[4];
    {
      float ssum = 0.f;
#pragma unroll
      for (int dy = 0; dy < 4; ++dy) {
        int y = 2 * h - 1 + dy;
        bool ok = (y >= 0) && (y < 128);
        iy[dy] = ok ? y : 0;
        float w0 = (dy == 0 || dy == 3) ? 0.125f : 0.375f;
        wy[dy] = ok ? w0 : 0.f;
        ssum += wy[dy];
      }
      float inv = 1.f / ssum;
#pragma unroll
      for (int dy = 0; dy < 4; ++dy) wy[dy] *= inv;
    }
    float wx[4];
    {
      float ssum = 0.f;
#pragma unroll
      for (int dx = 0; dx < 4; ++dx) {
        int xq = 2 * wq - 1 + dx;
        bool ok = (xq >= 0) && (xq < 128);
        float w0 = (dx == 0 || dx == 3) ? 0.125f : 0.375f;
        wx[dx] = ok ? w0 : 0.f;
        ssum += wx[dx];
      }
      float inv = 1.f / ssum;
#pragma unroll
      for (int dx = 0; dx < 4; ++dx) wx[dx] *= inv;
    }
    int syA, syB; float wsyA, wsyB;
    {
      int j0 = (h - 1) >> 1;
      float f = (h & 1) ? 0.25f : 0.75f;
      float a = 1.f - f, b2 = f;
      if (j0 < 0) a = 0.f;
      if (j0 + 1 > 31) b2 = 0.f;
      float inv = 1.f / (a + b2);
      wsyA = a * inv; wsyB = b2 * inv;
      syA = j0 < 0 ? 0 : j0;
      syB = (j0 + 1 > 31) ? 31 : (j0 + 1);
    }
    int sxA, sxB; float wsxA, wsxB;
    {
      int j0 = (wq - 1) >> 1;
      float f = (wq & 1) ? 0.25f : 0.75f;
      float a = 1.f - f, b2 = f;
      if (j0 < 0) a = 0.f;
      if (j0 + 1 > 31) b2 = 0.f;
      float inv = 1.f / (a + b2);
      wsxA = a * inv; wsxB = b2 * inv;
      sxA = j0 < 0 ? 0 : j0;
      sxB = (j0 + 1 > 31) ? 31 : (j0 + 1);
    }
#pragma unroll 4
    for (int ci = 0; ci < 16; ++ci) {
      int c = cq * 16 + ci;
      const float* lc = lp + ((size_t)(bb * 128 + c) << 14);
      float acc = 0.f;
#pragma unroll
      for (int dy = 0; dy < 4; ++dy) {
        const float* row = lc + (iy[dy] << 7);
        f32x2 v = *(const f32x2*)&row[2 * wq];
        float bprev = __shfl_up(v.y, 1);
        float anext = __shfl_down(v.x, 1);
        float rs = wx[0] * bprev + wx[1] * v.x + wx[2] * v.y + wx[3] * anext;
        acc = fmaf(wy[dy], rs, acc);
      }
      xin[wq][c] = (bf16)acc;
      xin[wq][128 + c] = (bf16)mp[((bb * 128 + c) * 64 + h) * 64 + wq];
      const float* sc = sp + ((size_t)(bb * 128 + c) << 10);
      float sv = wsyA * (wsxA * sc[(syA << 5) + sxA] + wsxB * sc[(syA << 5) + sxB]) +
                 wsyB * (wsxA * sc[(syB << 5) + sxA] + wsxB * sc[(syB << 5) + sxB]);
      xin[wq][256 + c] = (bf16)sv;
    }
  }
  __syncthreads();

  // ---- phase B: MFMA proj_in (M=128 out-ch over 8 waves, N=64 w, K=384) ----
  const int lane = tid & 63, wv = tid >> 6;
  const int l16 = lane & 15, k8 = (lane >> 4) * 8, j4 = (lane >> 4) * 4;
  const f32x4 zf = {0.f, 0.f, 0.f, 0.f};
  f32x4 acc[4];
#pragma unroll
  for (int pt = 0; pt < 4; ++pt) acc[pt] = zf;

  for (int kk = 0; kk < 12; ++kk) {
    bf16x8 bfr[4];
#pragma unroll
    for (int pt = 0; pt < 4; ++pt)
      bfr[pt] = *(const bf16x8*)&xin[pt * 16 + l16][kk * 32 + k8];
    bf16x8 afr = *(const bf16x8*)(Wpi + (size_t)(wv * 16 + l16) * 384 + kk * 32 + k8);
#pragma unroll
    for (int pt = 0; pt < 4; ++pt) acc[pt] = mfma16(afr, bfr[pt], acc[pt]);
  }
  {
    int c0 = wv * 16 + j4;
    f32x4 scv = *(const f32x4*)&pscale[c0];
    f32x4 shv = *(const f32x4*)&pshift[c0];
#pragma unroll
    for (int pt = 0; pt < 4; ++pt) {
      int pw = pt * 16 + l16;
      bf16x4 pk;
#pragma unroll
      for (int j = 0; j < 4; ++j) {
        float v = fmaxf(acc[pt][j] * scv[j] + shv[j], 0.f);
        xf16[(size_t)((bb * 128 + c0 + j) * 64 + h) * 64 + pw] = (f16)v;
        pk[j] = (bf16)v;
      }
      *(bf16x4*)&xb[(size_t)(bb * 4096 + h * 64 + pw) * 128 + c0] = pk;
      *(bf16x4*)&xbT[(size_t)(bb * 4096 + pw * 64 + h) * 128 + c0] = pk;
    }
  }
}

// ---------------------------------------------------------------------------
// K2: gx = x*wih^T + bih (+bhh for r,z) in scan-fragment layout:
//   gx[t][nb][part 0..2][tid 0..511][4] f16, part = r|z|n.
// ---------------------------------------------------------------------------
__global__ __launch_bounds__(512, 2) void k_gx(
    const bf16* __restrict__ xb, const bf16* __restrict__ xbT,
    const bf16* __restrict__ wih_h_b, const bf16* __restrict__ wih_w_b,
    const float* __restrict__ bih_h, const float* __restrict__ bih_w,
    const float* __restrict__ bhh_h, const float* __restrict__ bhh_w,
    f16* __restrict__ gxh, f16* __restrict__ gxw) {
  const int dir = blockIdx.z;
  const int nb = blockIdx.y;
  const int t0 = blockIdx.x * 2;
  const bf16* xsrc = dir ? xbT : xb;
  const bf16* wih = dir ? wih_w_b : wih_h_b;
  const float* bih = dir ? bih_w : bih_h;
  const float* bhh = dir ? bhh_w : bhh_h;
  f16* gx = dir ? gxw : gxh;

  const int tid = threadIdx.x, lane = tid & 63, w = tid >> 6;
  const int l16 = lane & 15, k8 = (lane >> 4) * 8, j4 = (lane >> 4) * 4;
  const int n = nb * 16 + l16;
  const int pb = n >> 6, q = n & 63;

  bf16x8 afr[3][4];
#pragma unroll
  for (int part = 0; part < 3; ++part) {
    int gbase = part * 128 + w * 16;
#pragma unroll
    for (int kk = 0; kk < 4; ++kk)
      afr[part][kk] = *(const bf16x8*)(wih + (size_t)(gbase + l16) * 128 + kk * 32 + k8);
  }
  const f32x4 zf = {0.f, 0.f, 0.f, 0.f};
  f32x4 acc[3][2];
#pragma unroll
  for (int part = 0; part < 3; ++part) { acc[part][0] = zf; acc[part][1] = zf; }

#pragma unroll
  for (int pt = 0; pt < 2; ++pt) {
    const bf16* xr = xsrc + (size_t)(pb * 4096 + (t0 + pt) * 64 + q) * 128;
#pragma unroll
    for (int kk = 0; kk < 4; ++kk) {
      bf16x8 bfr = *(const bf16x8*)(xr + kk * 32 + k8);
#pragma unroll
      for (int part = 0; part < 3; ++part)
        acc[part][pt] = mfma16(afr[part][kk], bfr, acc[part][pt]);
    }
  }
#pragma unroll
  for (int part = 0; part < 3; ++part) {
    int g0 = part * 128 + w * 16 + j4;
    f32x4 bi = *(const f32x4*)&bih[g0];
    if (part < 2) {
      f32x4 bh = *(const f32x4*)&bhh[g0];
#pragma unroll
      for (int j = 0; j < 4; ++j) bi[j] += bh[j];
    }
#pragma unroll
    for (int pt = 0; pt < 2; ++pt) {
      f16x4 pk;
#pragma unroll
      for (int j = 0; j < 4; ++j) pk[j] = (f16)(acc[part][pt][j] + bi[j]);
      *(f16x4*)&gx[((size_t)(((t0 + pt) * 32 + nb) * 3 + part) * 512 + tid) * 4] = pk;
    }
  }
}

// ---------------------------------------------------------------------------
// K3: GRU scans. 64 blocks x 512 threads (8 waves, 2/SIMD).
// LDS-only barrier (raw s_barrier + bare lgkmcnt(0), sched_barrier fences):
// gx prefetch loads + output stores stay in flight across steps.
// t-loop unrolled x4; gq[4][3] static prefetch ring, depth 2.
// ---------------------------------------------------------------------------
__global__ __launch_bounds__(512, 2) void k_scan(
    const bf16* __restrict__ whh_h_b, const bf16* __restrict__ whh_w_b,
    const float* __restrict__ bhh_h, const float* __restrict__ bhh_w,
    const f16* __restrict__ gxh, const f16* __restrict__ gxw,
    f16* __restrict__ ohb, f16* __restrict__ owb) {
  const int dir = blockIdx.x >> 5;
  const int nb = blockIdx.x & 31;
  const bf16* whh = dir ? whh_w_b : whh_h_b;
  const float* bhh = dir ? bhh_w : bhh_h;
  const f16* gx = dir ? gxw : gxh;
  f16* outb = dir ? owb : ohb;

  __shared__ __align__(16) bf16 hbuf[2][16][136];

  const int tid = threadIdx.x, lane = tid & 63, w = tid >> 6;
  const int l16 = lane & 15, k8 = (lane >> 4) * 8, j4 = (lane >> 4) * 4;
  const int cc0 = w * 16 + j4;

  bf16x8 afr[3][4];
#pragma unroll
  for (int part = 0; part < 3; ++part) {
    int gbase = part * 128 + w * 16;
#pragma unroll
    for (int kk = 0; kk < 4; ++kk)
      afr[part][kk] = *(const bf16x8*)(whh + (size_t)(gbase + l16) * 128 + kk * 32 + k8);
  }
  const f32x4 bhn = *(const f32x4*)&bhh[256 + cc0];

  for (int i = tid; i < 2 * 16 * 136; i += 512) ((bf16*)hbuf)[i] = (bf16)0.f;

  const int n = nb * 16 + l16;
  const int pb = n >> 6, q = n & 63;
  const int pbase0 = pb * 4096 + (dir ? q * 64 : q);
  const int pstep = dir ? 1 : 64;

  // prefetch ring: gq[u][part], u = t & 3; preload t=0,1
  f16x4 gq[4][3];
#pragma unroll
  for (int tp = 0; tp < 2; ++tp) {
    const size_t b0 = ((size_t)(tp * 32 + nb) * 3) * 512 + tid;
    gq[tp][0] = *(const f16x4*)&gx[b0 * 4];
    gq[tp][1] = *(const f16x4*)&gx[(b0 + 512) * 4];
    gq[tp][2] = *(const f16x4*)&gx[(b0 + 1024) * 4];
  }
  f32x4 hreg = {0.f, 0.f, 0.f, 0.f};

  // initial LDS-only barrier (prefetch loads stay in flight)
  __builtin_amdgcn_sched_barrier(0);
  asm volatile("s_waitcnt lgkmcnt(0)");
  __builtin_amdgcn_s_barrier();
  __builtin_amdgcn_sched_barrier(0);

  const f32x4 zf = {0.f, 0.f, 0.f, 0.f};
  for (int tb = 0; tb < 16; ++tb) {
#pragma unroll
    for (int u = 0; u < 4; ++u) {
      const int t = tb * 4 + u;
      {  // issue prefetch for t+2 (consumed two barriers later)
        int tp = t + 2 < 64 ? t + 2 : 63;
        const size_t b0 = ((size_t)(tp * 32 + nb) * 3) * 512 + tid;
        gq[(u + 2) & 3][0] = *(const f16x4*)&gx[b0 * 4];
        gq[(u + 2) & 3][1] = *(const f16x4*)&gx[(b0 + 512) * 4];
        gq[(u + 2) & 3][2] = *(const f16x4*)&gx[(b0 + 1024) * 4];
      }
      const int cur = u & 1;
      bf16x8 hb[4];
#pragma unroll
      for (int kk = 0; kk < 4; ++kk)
        hb[kk] = *(const bf16x8*)&hbuf[cur][l16][kk * 32 + k8];
      f32x4 aR = zf, aZ = zf, aN = zf;
#pragma unroll
      for (int kk = 0; kk < 4; ++kk) {
        aR = mfma16(afr[0][kk], hb[kk], aR);
        aZ = mfma16(afr[1][kk], hb[kk], aZ);
        aN = mfma16(afr[2][kk], hb[kk], aN);
      }
      bf16x4 hb4;
      f16x4 o4;
#pragma unroll
      for (int j = 0; j < 4; ++j) {
        float r = sigm((float)gq[u][0][j] + aR[j]);
        float z = sigm((float)gq[u][1][j] + aZ[j]);
        float nn = tanh_fast((float)gq[u][2][j] + r * (aN[j] + bhn[j]));
        float h = nn + z * (hreg[j] - nn);
        hreg[j] = h;
        hb4[j] = (bf16)h;
        o4[j] = (f16)h;
      }
      *(bf16x4*)&hbuf[cur ^ 1][l16][cc0] = hb4;
      *(f16x4*)&outb[(size_t)(pbase0 + t * pstep) * 128 + cc0] = o4;
      // LDS-only barrier: ds_write drained; vmem (gx loads, outb stores) not
      __builtin_amdgcn_sched_barrier(0);
      asm volatile("s_waitcnt lgkmcnt(0)");
      __builtin_amdgcn_s_barrier();
      __builtin_amdgcn_sched_barrier(0);
    }
  }
}

// ---------------------------------------------------------------------------
// K4: scanned = oh+ow; gate = sigmoid(scanned@gate_w^T+b); gated = scanned*gate;
// out = relu(gated@proj_out^T * scale + shift) + x.  One (b,h) row per block.
// ---------------------------------------------------------------------------
__global__ __launch_bounds__(256, 2) void k_final(
    const f16* __restrict__ ohb, const f16* __restrict__ owb,
    const bf16* __restrict__ Wg, const float* __restrict__ gate_b,
    const bf16* __restrict__ Wpo, const float* __restrict__ poscale,
    const float* __restrict__ poshift, const f16* __restrict__ xf16,
    float* __restrict__ out) {
  __shared__ __align__(16) float sf[64][132];
  __shared__ __align__(16) bf16 sb[64][136];
  __shared__ __align__(16) bf16 gbuf[64][136];
  const int tid = threadIdx.x;
  const int bb = blockIdx.x >> 6, h = blockIdx.x & 63;
  const int pbase = bb * 4096 + h * 64;
  for (int i = tid; i < 2048; i += 256) {
    int w = i >> 5, cg = (i & 31) * 4;
    size_t idx = (size_t)(pbase + w) * 128 + cg;
    f16x4 a = *(const f16x4*)&ohb[idx];
    f16x4 b = *(const f16x4*)&owb[idx];
    f32x4 v;
    bf16x4 pk;
#pragma unroll
    for (int j = 0; j < 4; ++j) {
      v[j] = (float)a[j] + (float)b[j];
      pk[j] = (bf16)v[j];
    }
    *(f32x4*)&sf[w][cg] = v;
    *(bf16x4*)&sb[w][cg] = pk;
  }
  __syncthreads();
  const int lane = tid & 63, wv = tid >> 6;
  const int l16 = lane & 15, k8 = (lane >> 4) * 8, j4 = (lane >> 4) * 4;
  const f32x4 zf = {0.f, 0.f, 0.f, 0.f};
  f32x4 acc[2][4];
#pragma unroll
  for (int i = 0; i < 2; ++i)
#pragma unroll
    for (int pt = 0; pt < 4; ++pt) acc[i][pt] = zf;
#pragma unroll
  for (int kk = 0; kk < 4; ++kk) {
    bf16x8 bfr[4];
#pragma unroll
    for (int pt = 0; pt < 4; ++pt)
      bfr[pt] = *(const bf16x8*)&sb[pt * 16 + l16][kk * 32 + k8];
#pragma unroll
    for (int i = 0; i < 2; ++i) {
      bf16x8 afr = *(const bf16x8*)(Wg + (size_t)((wv * 2 + i) * 16 + l16) * 128 + kk * 32 + k8);
#pragma unroll
      for (int pt = 0; pt < 4; ++pt) acc[i][pt] = mfma16(afr, bfr[pt], acc[i][pt]);
    }
  }
#pragma unroll
  for (int i = 0; i < 2; ++i) {
    int o0 = (wv * 2 + i) * 16 + j4;
    f32x4 gb4 = *(const f32x4*)&gate_b[o0];
#pragma unroll
    for (int pt = 0; pt < 4; ++pt) {
      int pc = pt * 16 + l16;
      f32x4 sv = *(const f32x4*)&sf[pc][o0];
      bf16x4 pk;
#pragma unroll
      for (int j = 0; j < 4; ++j) {
        float g = sigm(acc[i][pt][j] + gb4[j]);
        pk[j] = (bf16)(sv[j] * g);
      }
      *(bf16x4*)&gbuf[pc][o0] = pk;
    }
  }
  __syncthreads();
  f32x4 acc2[2][4];
#pragma unroll
  for (int i = 0; i < 2; ++i)
#pragma unroll
    for (int pt = 0; pt < 4; ++pt) acc2[i][pt] = zf;
#pragma unroll
  for (int kk = 0; kk < 4; ++kk) {
    bf16x8 bfr[4];
#pragma unroll
    for (int pt = 0; pt < 4; ++pt)
      bfr[pt] = *(const bf16x8*)&gbuf[pt * 16 + l16][kk * 32 + k8];
#pragma unroll
    for (int i = 0; i < 2; ++i) {
      bf16x8 afr = *(const bf16x8*)(Wpo + (size_t)((wv * 2 + i) * 16 + l16) * 128 + kk * 32 + k8);
#pragma unroll
      for (int pt = 0; pt < 4; ++pt) acc2[i][pt] = mfma16(afr, bfr[pt], acc2[i][pt]);
    }
  }
#pragma unroll
  for (int i = 0; i < 2; ++i) {
    int o0 = (wv * 2 + i) * 16 + j4;
    f32x4 scv = *(const f32x4*)&poscale[o0];
    f32x4 shv = *(const f32x4*)&poshift[o0];
#pragma unroll
    for (int pt = 0; pt < 4; ++pt) {
      int pc = pt * 16 + l16;
#pragma unroll
      for (int j = 0; j < 4; ++j) {
        int oc = o0 + j;
        size_t oi = (size_t)((bb * 128 + oc) * 64 + h) * 64 + pc;
        float v = fmaxf(acc2[i][pt][j] * scv[j] + shv[j], 0.f) + (float)xf16[oi];
        out[oi] = v;
      }
    }
  }
}

// ---------------------------------------------------------------------------
// ws layout (bytes), total 92,831,744:
//   [0,        557056)     weights bf16
//   [557056,   8945664)    x f16  [b][c][h][w]   (residual)
//   [8945664,  17334272)   xb bf16 [b,h,w][c]
//   [17334272, 25722880)   xbT bf16 [b,w,h][c]
//   [25722880, 50888704)   gx_h f16 [t][nb][3][512][4]
//   [50888704, 76054528)   gx_w f16
//   [76054528, 84443136)   oh f16 [p][c]
//   [84443136, 92831744)   ow f16
// ---------------------------------------------------------------------------
extern "C" void kernel_launch(void* const* d_in, const int* in_sizes, int n_in,
                              void* d_out, int out_size, void* d_ws, size_t ws_size,
                              hipStream_t stream) {
  const float* lp = (const float*)d_in[0];
  const float* mp = (const float*)d_in[1];
  const float* sp = (const float*)d_in[2];
  const float* proj_in_w = (const float*)d_in[3];
  const float* proj_in_scale = (const float*)d_in[4];
  const float* proj_in_shift = (const float*)d_in[5];
  const float* wih_h = (const float*)d_in[6];
  const float* whh_h = (const float*)d_in[7];
  const float* bih_h = (const float*)d_in[8];
  const float* bhh_h = (const float*)d_in[9];
  const float* wih_w = (const float*)d_in[10];
  const float* whh_w = (const float*)d_in[11];
  const float* bih_w = (const float*)d_in[12];
  const float* bhh_w = (const float*)d_in[13];
  const float* gate_w = (const float*)d_in[14];
  const float* gate_b = (const float*)d_in[15];
  const float* proj_out_w = (const float*)d_in[16];
  const float* proj_out_scale = (const float*)d_in[17];
  const float* proj_out_shift = (const float*)d_in[18];
  float* out = (float*)d_out;

  char* ws = (char*)d_ws;
  bf16* wb = (bf16*)ws;
  bf16* Wpi_b = wb + 0;
  bf16* Wih_h_b = wb + 49152;
  bf16* Whh_h_b = wb + 98304;
  bf16* Wih_w_b = wb + 147456;
  bf16* Whh_w_b = wb + 196608;
  bf16* Wg_b = wb + 245760;
  bf16* Wpo_b = wb + 262144;
  f16* xf16 = (f16*)(ws + 557056);
  bf16* xb = (bf16*)(ws + 8945664);
  bf16* xbT = (bf16*)(ws + 17334272);
  f16* gxh = (f16*)(ws + 25722880);
  f16* gxw = (f16*)(ws + 50888704);
  f16* ohb = (f16*)(ws + 76054528);
  f16* owb = (f16*)(ws + 84443136);

  k_prep<<<dim3(1088), dim3(256), 0, stream>>>(proj_in_w, wih_h, whh_h, wih_w,
                                               whh_w, gate_w, proj_out_w, wb);
  k_projin<<<dim3(512), dim3(512), 0, stream>>>(lp, mp, sp, proj_in_scale,
                                                proj_in_shift, Wpi_b, xf16, xb, xbT);
  k_gx<<<dim3(32, 32, 2), dim3(512), 0, stream>>>(xb, xbT, Wih_h_b, Wih_w_b,
                                                  bih_h, bih_w, bhh_h, bhh_w,
                                                  gxh, gxw);
  k_scan<<<dim3(64), dim3(512), 0, stream>>>(Whh_h_b, Whh_w_b, bhh_h, bhh_w,
                                             gxh, gxw, ohb, owb);
  k_final<<<dim3(512), dim3(256), 0, stream>>>(ohb, owb, Wg_b, gate_b, Wpo_b,
                                               proj_out_scale, proj_out_shift,
                                               xf16, out);
}